// Round 2
// baseline (5015.564 us; speedup 1.0000x reference)
//
#include <hip/hip_runtime.h>

typedef unsigned short u16;
typedef unsigned int u32;
typedef short v8s __attribute__((ext_vector_type(8)));
typedef float v4f __attribute__((ext_vector_type(4)));

#define B_SZ 8
#define HH 32
#define WW 32
#define NN 1024          // H*W
#define M1 (B_SZ * NN)   // 8192 rows (one direction)
#define M4 (4 * M1)      // 32768 rows (4 directions)

__device__ __forceinline__ float bf2f(u16 u) {
    u32 x = ((u32)u) << 16;
    return __builtin_bit_cast(float, x);
}
__device__ __forceinline__ u16 f2bf(float f) {
    u32 x = __builtin_bit_cast(u32, f);
    x = x + 0x7fffu + ((x >> 16) & 1u);
    return (u16)(x >> 16);
}
__device__ __forceinline__ float sigmoidf_(float x) { return 1.f / (1.f + __expf(-x)); }
// flag-aware raw-input readers (fin=1 -> input tensor is fp32, else bf16)
__device__ __forceinline__ float ldf(const void* p, size_t i, int fin) {
    return fin ? ((const float*)p)[i] : bf2f(((const u16*)p)[i]);
}
__device__ __forceinline__ u16 ldbf(const void* p, size_t i, int fin) {
    return fin ? f2bf(((const float*)p)[i]) : ((const u16*)p)[i];
}

// ---------------- input dtype sniffer ---------------------------------------
// bf16 N(0,1) data: every u16 has exponent-field bits in a narrow band.
// fp32 data: odd u16s (high halves) look like bf16, even u16s are uniform
// mantissa junk (~16% in band). 512 samples -> ok≈512 (bf16) vs ≈300 (fp32).
__global__ void detect_dtype(const u16* __restrict__ raw, int* __restrict__ flags) {
    if (threadIdx.x == 0 && blockIdx.x == 0) {
        int ok = 0;
        for (int i = 0; i < 512; i++) {
            int e = (raw[i] >> 7) & 0xFF;
            ok += (e >= 100 && e <= 140) ? 1 : 0;
        }
        flags[0] = (ok < 460) ? 1 : 0;
    }
}

__global__ __launch_bounds__(256) void convert_bf(const void* __restrict__ src,
                                                  u16* __restrict__ dst,
                                                  const int* __restrict__ flags, int n) {
    int fin = flags[0];
    int i = blockIdx.x * 256 + threadIdx.x;
    if (i < n) dst[i] = ldbf(src, (size_t)i, fin);
}

__global__ __launch_bounds__(256) void zero_f32(float* __restrict__ p, int n) {
    int i = blockIdx.x * 256 + threadIdx.x;
    if (i < n) p[i] = 0.f;
}

// ---------------- diagonal permutation init ---------------------------------
__global__ void diag_perm_init(int* __restrict__ perm, int* __restrict__ inv) {
    int t = blockIdx.x * blockDim.x + threadIdx.x;
    if (t >= NN) return;
    int i = t / WW, j = t % WW;
    int off = j - i;
    int start = 0;
    for (int o = -(HH - 1); o < off; ++o) {
        int lo = (0 > -o) ? 0 : -o;
        int hi = (HH - 1 < WW - 1 - o) ? (HH - 1) : (WW - 1 - o);
        start += (hi - lo + 1);
    }
    int lo0 = (0 > -off) ? 0 : -off;
    int r = start + (i - lo0);
    perm[r] = t;   // perm[rank] = linear index (gather AND scatter map)
    inv[t] = r;
}

// ---------------- weight transpose+pad: src (K x Nsrc) -> dst (Npad x K) ----
__global__ __launch_bounds__(256) void transpose_pad(const void* __restrict__ src,
                                                     u16* __restrict__ dst,
                                                     int K, int Nsrc,
                                                     const int* __restrict__ flags) {
    int fin = flags[0];
    __shared__ u16 tile[32][33];
    int k0 = blockIdx.x * 32, n0 = blockIdx.y * 32;
    int tx = threadIdx.x & 31, ty = threadIdx.x >> 5;  // ty 0..7
#pragma unroll
    for (int i = 0; i < 4; i++) {
        int k = k0 + ty + i * 8, n = n0 + tx;
        tile[ty + i * 8][tx] = (n < Nsrc) ? ldbf(src, (size_t)k * Nsrc + n, fin) : (u16)0;
    }
    __syncthreads();
#pragma unroll
    for (int i = 0; i < 4; i++) {
        int n = n0 + ty + i * 8, k = k0 + tx;
        dst[(size_t)n * K + k] = tile[tx][ty + i * 8];
    }
}

// ---------------- generic MFMA GEMM:  C(MxN) = A(MxK) * Bt(NxK)^T -----------
// AM: 0 = plain rows (lda=K), 1 = direction gather from x (lda=1024, dir=dbase+(r>>13))
// EM: 0 = bf16 store                     (out0)
//     1 = split xz -> xi,z bf16          (out0,out1), N=2048
//     2 = fp32 store                     (out0)
//     3 = scatter-accumulate into facc   (out0=facc fp32, aux0=dir_w raw, dir=dbase)
//     4 = final: out = vf + g*acc        (out0, aux0=vf raw, aux1=g; dtype per flag)
template <int AM, int EM>
__global__ __launch_bounds__(256) void gemm_bt(const u16* __restrict__ A,
                                               const u16* __restrict__ Bt,
                                               void* __restrict__ out0,
                                               void* __restrict__ out1,
                                               int M, int N, int K,
                                               const int* __restrict__ perm3,
                                               const int* __restrict__ flags,
                                               int dbase,
                                               const void* __restrict__ aux0,
                                               const float* __restrict__ aux1) {
    int fin = flags[0];
    __shared__ u16 As[64][32];
    __shared__ u16 Bs[64][32];
    int tid = threadIdx.x;
    int wave = tid >> 6, lane = tid & 63, quad = lane >> 4, l16 = lane & 15;
    int m0 = blockIdx.x * 64, n0 = blockIdx.y * 64;
    int lr = tid >> 2, seg = (tid & 3) * 8;  // 4 threads per row, 8 elems each

    const u16* arow;
    {
        int r = m0 + lr;
        if (AM == 1) {
            int d = dbase + (r >> 13), t = r & 1023, b = (r >> 10) & 7;
            int ts;
            if (d == 0) ts = t;
            else if (d == 1) ts = (NN - 1) - t;
            else if (d == 2) ts = (t & (HH - 1)) * WW + (t >> 5);  // transpose perm
            else ts = perm3[t];
            arow = A + ((size_t)(b * NN + ts)) * 1024;
        } else {
            arow = A + (size_t)r * K;
        }
    }
    const u16* brow = Bt + (size_t)(n0 + lr) * K;

    v4f acc[4];
#pragma unroll
    for (int j = 0; j < 4; j++) acc[j] = (v4f){0.f, 0.f, 0.f, 0.f};

    for (int k0 = 0; k0 < K; k0 += 32) {
        uint4 av = *(const uint4*)(arow + k0 + seg);
        uint4 bv = *(const uint4*)(brow + k0 + seg);
        *(uint4*)&As[lr][seg] = av;
        *(uint4*)&Bs[lr][seg] = bv;
        __syncthreads();
        v8s af = *(const v8s*)&As[wave * 16 + l16][quad * 8];
#pragma unroll
        for (int j = 0; j < 4; j++) {
            v8s bf = *(const v8s*)&Bs[j * 16 + l16][quad * 8];
            acc[j] = __builtin_amdgcn_mfma_f32_16x16x32_bf16(af, bf, acc[j], 0, 0, 0);
        }
        __syncthreads();
    }

#pragma unroll
    for (int j = 0; j < 4; j++) {
#pragma unroll
        for (int r = 0; r < 4; r++) {
            int row = m0 + wave * 16 + quad * 4 + r;
            int col = n0 + j * 16 + l16;
            float v = acc[j][r];
            size_t oi = (size_t)row * N + col;
            if (EM == 0) {
                ((u16*)out0)[oi] = f2bf(v);
            } else if (EM == 1) {
                if (col < 1024) ((u16*)out0)[(size_t)row * 1024 + col] = f2bf(v);
                else ((u16*)out1)[(size_t)row * 1024 + (col - 1024)] = f2bf(v);
            } else if (EM == 2) {
                ((float*)out0)[oi] = v;
            } else if (EM == 3) {
                // scatter row t of direction d to spatial position q = P_d(t)
                int b2 = row >> 10, t = row & 1023;
                int q;
                if (dbase == 0) q = t;
                else if (dbase == 1) q = (NN - 1) - t;
                else if (dbase == 2) q = (t & (HH - 1)) * WW + (t >> 5);
                else q = perm3[t];
                float w = ldf(aux0, dbase, fin);
                ((float*)out0)[((size_t)(b2 * NN + q)) * 1024 + col] += w * v;
            } else {
                float g = aux1[row >> 10];
                float res = ldf(aux0, oi, fin) + g * v;
                if (fin) ((float*)out0)[oi] = res;
                else ((u16*)out0)[oi] = f2bf(res);
            }
        }
    }
}

// ---------------- depthwise causal conv (k=4) + SiLU ------------------------
__global__ __launch_bounds__(256) void conv_silu(const u16* __restrict__ xi,
                                                 const void* __restrict__ cw,
                                                 u16* __restrict__ xc,
                                                 const int* __restrict__ flags) {
    int fin = flags[0];
    int idx = blockIdx.x * 256 + threadIdx.x;
    int e = idx & 1023;
    int row = idx >> 10;
    int t = row & 1023;
    float acc = 0.f;
#pragma unroll
    for (int k = 0; k < 4; k++) {
        int tt = t - 3 + k;
        if (tt >= 0) acc += ldf(cw, (size_t)e * 4 + k, fin) *
                            bf2f(xi[(size_t)(row - 3 + k) * 1024 + e]);
    }
    xc[idx] = f2bf(acc * sigmoidf_(acc));
}

// ---------------- selective scan (dt-matvec fused; yz written over xc) ------
__global__ __launch_bounds__(256) void scan_kernel(const float* __restrict__ dtbc,
                                                   u16* __restrict__ xcyz,
                                                   const u16* __restrict__ zb,
                                                   const void* __restrict__ A_log,
                                                   const void* __restrict__ W_dt,
                                                   const void* __restrict__ b_dt,
                                                   const int* __restrict__ flags) {
    int fin = flags[0];
    int dbi = blockIdx.x >> 2;                        // sequence index
    int e = (blockIdx.x & 3) * 256 + threadIdx.x;     // 0..1023
    float Ae[16], wdt[16];
#pragma unroll
    for (int s = 0; s < 16; s++) Ae[s] = -__expf(ldf(A_log, (size_t)e * 16 + s, fin));
#pragma unroll
    for (int s = 0; s < 16; s++) wdt[s] = ldf(W_dt, (size_t)s * 1024 + e, fin);
    float bd = ldf(b_dt, e, fin);
    float h[16];
#pragma unroll
    for (int s = 0; s < 16; s++) h[s] = 0.f;
    size_t rowbase = (size_t)dbi * 1024;
    for (int t = 0; t < 1024; t++) {
        size_t row = rowbase + t;
        const float4* q = (const float4*)(dtbc + row * 64);
        float4 c0 = q[0], c1 = q[1], c2 = q[2], c3 = q[3];
        float xp = bd;
        xp += c0.x * wdt[0] + c0.y * wdt[1] + c0.z * wdt[2] + c0.w * wdt[3];
        xp += c1.x * wdt[4] + c1.y * wdt[5] + c1.z * wdt[6] + c1.w * wdt[7];
        xp += c2.x * wdt[8] + c2.y * wdt[9] + c2.z * wdt[10] + c2.w * wdt[11];
        xp += c3.x * wdt[12] + c3.y * wdt[13] + c3.z * wdt[14] + c3.w * wdt[15];
        float dt = (xp > 15.f) ? xp : log1pf(__expf(xp));   // softplus
        float4 b0 = q[4], b1 = q[5], b2 = q[6], b3 = q[7];
        float bc[16] = {b0.x, b0.y, b0.z, b0.w, b1.x, b1.y, b1.z, b1.w,
                        b2.x, b2.y, b2.z, b2.w, b3.x, b3.y, b3.z, b3.w};
        size_t ix = row * 1024 + e;
        float xv = bf2f(xcyz[ix]);
        float acc = 0.f;
#pragma unroll
        for (int s = 0; s < 16; s++) {
            h[s] = h[s] * __expf(Ae[s] * dt) + bc[s] * xv;
            acc += h[s];
        }
        float zv = bf2f(zb[ix]);
        xcyz[ix] = f2bf(acc * (zv * sigmoidf_(zv)));   // in-place: y*silu(z)
    }
}

// ---------------- LayerNorm over fused fp32 accumulator ---------------------
__global__ __launch_bounds__(256) void ln_kernel(const float* __restrict__ facc,
                                                 const void* __restrict__ ln_g,
                                                 const void* __restrict__ ln_b,
                                                 const int* __restrict__ flags,
                                                 u16* __restrict__ fn) {
    int fin = flags[0];
    size_t base = (size_t)blockIdx.x * 1024;
    float v[4];
    float sum = 0.f, sq = 0.f;
#pragma unroll
    for (int k = 0; k < 4; k++) {
        int e = threadIdx.x + k * 256;
        float f = facc[base + e];
        v[k] = f;
        sum += f;
        sq += f * f;
    }
    __shared__ float r1[256], r2[256];
    r1[threadIdx.x] = sum;
    r2[threadIdx.x] = sq;
    __syncthreads();
    for (int s = 128; s > 0; s >>= 1) {
        if (threadIdx.x < s) {
            r1[threadIdx.x] += r1[threadIdx.x + s];
            r2[threadIdx.x] += r2[threadIdx.x + s];
        }
        __syncthreads();
    }
    float mu = r1[0] * (1.f / 1024.f);
    float var = r2[0] * (1.f / 1024.f) - mu * mu;
    float rs = rsqrtf(var + 1e-5f);
#pragma unroll
    for (int k = 0; k < 4; k++) {
        int e = threadIdx.x + k * 256;
        fn[base + e] = f2bf((v[k] - mu) * rs * ldf(ln_g, e, fin) + ldf(ln_b, e, fin));
    }
}

// ---------------- per-batch gate scalar -------------------------------------
__global__ __launch_bounds__(256) void gate_kernel(const u16* __restrict__ vfb,
                                                   const void* __restrict__ Wg1,
                                                   const void* __restrict__ Wg2,
                                                   const int* __restrict__ flags,
                                                   float* __restrict__ g) {
    int fin = flags[0];
    __shared__ float meanv[1024];
    __shared__ float g1[256];
    int b = blockIdx.x;
    const u16* base = vfb + (size_t)b * NN * 1024;
#pragma unroll
    for (int k = 0; k < 4; k++) {
        int col = threadIdx.x + k * 256;
        float s = 0.f;
        for (int t = 0; t < NN; t++) s += bf2f(base[(size_t)t * 1024 + col]);
        meanv[col] = s * (1.f / (float)NN);
    }
    __syncthreads();
    int j = threadIdx.x;
    float a = 0.f;
    for (int k = 0; k < 1024; k++) a += meanv[k] * ldf(Wg1, (size_t)k * 256 + j, fin);
    float si = a * sigmoidf_(a);
    g1[j] = si * ldf(Wg2, j, fin);
    __syncthreads();
    for (int s = 128; s > 0; s >>= 1) {
        if (j < s) g1[j] += g1[j + s];
        __syncthreads();
    }
    if (j == 0) g[b] = sigmoidf_(g1[0]);
}

// ---------------- launch ----------------------------------------------------
extern "C" void kernel_launch(void* const* d_in, const int* in_sizes, int n_in,
                              void* d_out, int out_size, void* d_ws, size_t ws_size,
                              hipStream_t stream) {
    const void* vf_raw  = d_in[0];
    const void* W_input = d_in[1];
    const void* W_in    = d_in[2];
    const void* conv_w  = d_in[3];
    const void* W_xproj = d_in[4];
    const void* W_dt    = d_in[5];
    const void* b_dt    = d_in[6];
    const void* A_log   = d_in[7];
    const void* W_outm  = d_in[8];
    const void* dir_w   = d_in[9];
    const void* ln_g    = d_in[10];
    const void* ln_b    = d_in[11];
    const void* W_outpj = d_in[12];
    const void* Wg1     = d_in[13];
    const void* Wg2     = d_in[14];

    char* ws = (char*)d_ws;
    size_t off = 0;
    auto alloc = [&](size_t bytes) -> void* {
        void* p = ws + off;
        off = (off + bytes + 255) & ~(size_t)255;
        return p;
    };
    int*   flags = (int*)alloc(256);
    int*   perm3 = (int*)alloc(NN * 4);
    int*   inv3  = (int*)alloc(NN * 4);
    u16*   WtI   = (u16*)alloc((size_t)1024 * 1024 * 2);
    u16*   WtIn  = (u16*)alloc((size_t)2048 * 1024 * 2);
    u16*   WtXp  = (u16*)alloc((size_t)64 * 1024 * 2);
    u16*   WtOm  = (u16*)alloc((size_t)1024 * 1024 * 2);
    u16*   WtOp  = (u16*)alloc((size_t)1024 * 1024 * 2);
    u16*   vfb   = (u16*)alloc((size_t)M1 * 1024 * 2);   // vf as bf16
    u16*   xbuf  = (u16*)alloc((size_t)M1 * 1024 * 2);   // x = vf @ W_input
    float* facc  = (float*)alloc((size_t)M1 * 1024 * 4); // fused accumulator
    float* gbuf  = (float*)alloc(64);

    // Direction-chunked buffers: batch all 4 directions only if ws allows.
    bool big = ws_size >= ((size_t)300 << 20);
    int D = big ? 4 : 1;
    u16*   xi   = (u16*)alloc((size_t)D * M1 * 1024 * 2);
    u16*   zb   = (u16*)alloc((size_t)D * M1 * 1024 * 2);
    u16*   xc   = (u16*)alloc((size_t)D * M1 * 1024 * 2); // becomes yz in-place
    float* dtbc = (float*)alloc((size_t)D * M1 * 64 * 4);
    // peak usage: big ~274 MB, small ~124 MB

    detect_dtype<<<1, 64, 0, stream>>>((const u16*)vf_raw, flags);
    convert_bf<<<(M1 * 1024) / 256, 256, 0, stream>>>(vf_raw, vfb, flags, M1 * 1024);
    diag_perm_init<<<4, 256, 0, stream>>>(perm3, inv3);
    transpose_pad<<<dim3(32, 32), 256, 0, stream>>>(W_input, WtI, 1024, 1024, flags);
    transpose_pad<<<dim3(32, 64), 256, 0, stream>>>(W_in, WtIn, 1024, 2048, flags);
    transpose_pad<<<dim3(32, 2), 256, 0, stream>>>(W_xproj, WtXp, 1024, 32, flags);
    transpose_pad<<<dim3(32, 32), 256, 0, stream>>>(W_outm, WtOm, 1024, 1024, flags);
    transpose_pad<<<dim3(32, 32), 256, 0, stream>>>(W_outpj, WtOp, 1024, 1024, flags);
    zero_f32<<<(M1 * 1024) / 256, 256, 0, stream>>>(facc, M1 * 1024);

    // x = vf @ W_input
    gemm_bt<0, 0><<<dim3(M1 / 64, 16), 256, 0, stream>>>(
        vfb, WtI, xbuf, nullptr, M1, 1024, 1024, perm3, flags, 0, nullptr, nullptr);

    if (big) {
        gemm_bt<1, 1><<<dim3(M4 / 64, 32), 256, 0, stream>>>(
            xbuf, WtIn, xi, zb, M4, 2048, 1024, perm3, flags, 0, nullptr, nullptr);
        conv_silu<<<M4 * 4, 256, 0, stream>>>(xi, conv_w, xc, flags);
        gemm_bt<0, 2><<<dim3(M4 / 64, 1), 256, 0, stream>>>(
            xc, WtXp, dtbc, nullptr, M4, 64, 1024, perm3, flags, 0, nullptr, nullptr);
        scan_kernel<<<128, 256, 0, stream>>>(dtbc, xc, zb, A_log, W_dt, b_dt, flags);
        for (int d = 0; d < 4; d++) {
            gemm_bt<0, 3><<<dim3(M1 / 64, 16), 256, 0, stream>>>(
                xc + (size_t)d * M1 * 1024, WtOm, facc, nullptr, M1, 1024, 1024,
                perm3, flags, d, dir_w, nullptr);
        }
    } else {
        for (int d = 0; d < 4; d++) {
            gemm_bt<1, 1><<<dim3(M1 / 64, 32), 256, 0, stream>>>(
                xbuf, WtIn, xi, zb, M1, 2048, 1024, perm3, flags, d, nullptr, nullptr);
            conv_silu<<<M1 * 4, 256, 0, stream>>>(xi, conv_w, xc, flags);
            gemm_bt<0, 2><<<dim3(M1 / 64, 1), 256, 0, stream>>>(
                xc, WtXp, dtbc, nullptr, M1, 64, 1024, perm3, flags, d, nullptr, nullptr);
            scan_kernel<<<32, 256, 0, stream>>>(dtbc, xc, zb, A_log, W_dt, b_dt, flags);
            gemm_bt<0, 3><<<dim3(M1 / 64, 16), 256, 0, stream>>>(
                xc, WtOm, facc, nullptr, M1, 1024, 1024, perm3, flags, d, dir_w, nullptr);
        }
    }

    gate_kernel<<<8, 256, 0, stream>>>(vfb, Wg1, Wg2, flags, gbuf);
    u16* fn = xi;  // xi dead after conv
    ln_kernel<<<M1, 256, 0, stream>>>(facc, ln_g, ln_b, flags, fn);
    // out = vf + g[b] * (fn @ W_outproj), dtype matching input dtype
    gemm_bt<0, 4><<<dim3(M1 / 64, 16), 256, 0, stream>>>(
        fn, WtOp, d_out, nullptr, M1, 1024, 1024, perm3, flags, 0, vf_raw, gbuf);
}

// Round 3
// 1649.589 us; speedup vs baseline: 3.0405x; 3.0405x over previous
//
#include <hip/hip_runtime.h>

typedef unsigned short u16;
typedef unsigned int u32;
typedef short v8s __attribute__((ext_vector_type(8)));
typedef float v4f __attribute__((ext_vector_type(4)));

#define B_SZ 8
#define HH 32
#define WW 32
#define NN 1024          // H*W
#define M1 (B_SZ * NN)   // 8192 rows (one direction)
#define NCHUNK 16
#define CLEN 64          // NCHUNK*CLEN = 1024

__device__ __forceinline__ float bf2f(u16 u) {
    u32 x = ((u32)u) << 16;
    return __builtin_bit_cast(float, x);
}
__device__ __forceinline__ u16 f2bf(float f) {
    u32 x = __builtin_bit_cast(u32, f);
    x = x + 0x7fffu + ((x >> 16) & 1u);
    return (u16)(x >> 16);
}
__device__ __forceinline__ float sigmoidf_(float x) { return 1.f / (1.f + __expf(-x)); }
// flag-aware raw-input readers (fin=1 -> input tensor is fp32, else bf16)
__device__ __forceinline__ float ldf(const void* p, size_t i, int fin) {
    return fin ? ((const float*)p)[i] : bf2f(((const u16*)p)[i]);
}
__device__ __forceinline__ u16 ldbf(const void* p, size_t i, int fin) {
    return fin ? f2bf(((const float*)p)[i]) : ((const u16*)p)[i];
}

// ---------------- input dtype sniffer ---------------------------------------
__global__ void detect_dtype(const u16* __restrict__ raw, int* __restrict__ flags) {
    if (threadIdx.x == 0 && blockIdx.x == 0) {
        int ok = 0;
        for (int i = 0; i < 512; i++) {
            int e = (raw[i] >> 7) & 0xFF;
            ok += (e >= 100 && e <= 140) ? 1 : 0;
        }
        flags[0] = (ok < 460) ? 1 : 0;
    }
}

__global__ __launch_bounds__(256) void convert_bf(const void* __restrict__ src,
                                                  u16* __restrict__ dst,
                                                  const int* __restrict__ flags, int n) {
    int fin = flags[0];
    int i = blockIdx.x * 256 + threadIdx.x;
    if (i < n) dst[i] = ldbf(src, (size_t)i, fin);
}

__global__ __launch_bounds__(256) void zero_f32(float* __restrict__ p, int n) {
    int i = blockIdx.x * 256 + threadIdx.x;
    if (i < n) p[i] = 0.f;
}

// ---------------- diagonal permutation init ---------------------------------
__global__ void diag_perm_init(int* __restrict__ perm, int* __restrict__ inv) {
    int t = blockIdx.x * blockDim.x + threadIdx.x;
    if (t >= NN) return;
    int i = t / WW, j = t % WW;
    int off = j - i;
    int start = 0;
    for (int o = -(HH - 1); o < off; ++o) {
        int lo = (0 > -o) ? 0 : -o;
        int hi = (HH - 1 < WW - 1 - o) ? (HH - 1) : (WW - 1 - o);
        start += (hi - lo + 1);
    }
    int lo0 = (0 > -off) ? 0 : -off;
    int r = start + (i - lo0);
    perm[r] = t;
    inv[t] = r;
}

// ---------------- weight transpose+pad: src (K x Nsrc) -> dst (Npad x K) ----
__global__ __launch_bounds__(256) void transpose_pad(const void* __restrict__ src,
                                                     u16* __restrict__ dst,
                                                     int K, int Nsrc,
                                                     const int* __restrict__ flags) {
    int fin = flags[0];
    __shared__ u16 tile[32][33];
    int k0 = blockIdx.x * 32, n0 = blockIdx.y * 32;
    int tx = threadIdx.x & 31, ty = threadIdx.x >> 5;
#pragma unroll
    for (int i = 0; i < 4; i++) {
        int k = k0 + ty + i * 8, n = n0 + tx;
        tile[ty + i * 8][tx] = (n < Nsrc) ? ldbf(src, (size_t)k * Nsrc + n, fin) : (u16)0;
    }
    __syncthreads();
#pragma unroll
    for (int i = 0; i < 4; i++) {
        int n = n0 + ty + i * 8, k = k0 + tx;
        dst[(size_t)n * K + k] = tile[tx][ty + i * 8];
    }
}

// ---------------- generic MFMA GEMM:  C(MxN) = A(MxK) * Bt(NxK)^T -----------
// AM: 0 = plain rows (lda=K), 1 = direction gather from x (lda=1024, dir=dbase)
// EM: 0 = bf16 store; 1 = split xz->xi,z; 2 = fp32 store;
//     3 = scatter-accumulate into facc (dir=dbase, aux0=dir_w raw);
//     4 = final: out = vf + g*acc (aux0=vf raw, aux1=g; out dtype per flag)
template <int AM, int EM>
__global__ __launch_bounds__(256) void gemm_bt(const u16* __restrict__ A,
                                               const u16* __restrict__ Bt,
                                               void* __restrict__ out0,
                                               void* __restrict__ out1,
                                               int M, int N, int K,
                                               const int* __restrict__ perm3,
                                               const int* __restrict__ flags,
                                               int dbase,
                                               const void* __restrict__ aux0,
                                               const float* __restrict__ aux1) {
    int fin = flags[0];
    __shared__ u16 As[64][32];
    __shared__ u16 Bs[64][32];
    int tid = threadIdx.x;
    int wave = tid >> 6, lane = tid & 63, quad = lane >> 4, l16 = lane & 15;
    int m0 = blockIdx.x * 64, n0 = blockIdx.y * 64;
    int lr = tid >> 2, seg = (tid & 3) * 8;

    const u16* arow;
    {
        int r = m0 + lr;
        if (AM == 1) {
            int d = dbase, t = r & 1023, b = (r >> 10) & 7;
            int ts;
            if (d == 0) ts = t;
            else if (d == 1) ts = (NN - 1) - t;
            else if (d == 2) ts = (t & (HH - 1)) * WW + (t >> 5);
            else ts = perm3[t];
            arow = A + ((size_t)(b * NN + ts)) * 1024;
        } else {
            arow = A + (size_t)r * K;
        }
    }
    const u16* brow = Bt + (size_t)(n0 + lr) * K;

    v4f acc[4];
#pragma unroll
    for (int j = 0; j < 4; j++) acc[j] = (v4f){0.f, 0.f, 0.f, 0.f};

    for (int k0 = 0; k0 < K; k0 += 32) {
        uint4 av = *(const uint4*)(arow + k0 + seg);
        uint4 bv = *(const uint4*)(brow + k0 + seg);
        *(uint4*)&As[lr][seg] = av;
        *(uint4*)&Bs[lr][seg] = bv;
        __syncthreads();
        v8s af = *(const v8s*)&As[wave * 16 + l16][quad * 8];
#pragma unroll
        for (int j = 0; j < 4; j++) {
            v8s bf = *(const v8s*)&Bs[j * 16 + l16][quad * 8];
            acc[j] = __builtin_amdgcn_mfma_f32_16x16x32_bf16(af, bf, acc[j], 0, 0, 0);
        }
        __syncthreads();
    }

#pragma unroll
    for (int j = 0; j < 4; j++) {
#pragma unroll
        for (int r = 0; r < 4; r++) {
            int row = m0 + wave * 16 + quad * 4 + r;
            int col = n0 + j * 16 + l16;
            float v = acc[j][r];
            size_t oi = (size_t)row * N + col;
            if (EM == 0) {
                ((u16*)out0)[oi] = f2bf(v);
            } else if (EM == 1) {
                if (col < 1024) ((u16*)out0)[(size_t)row * 1024 + col] = f2bf(v);
                else ((u16*)out1)[(size_t)row * 1024 + (col - 1024)] = f2bf(v);
            } else if (EM == 2) {
                ((float*)out0)[oi] = v;
            } else if (EM == 3) {
                int b2 = row >> 10, t = row & 1023;
                int q;
                if (dbase == 0) q = t;
                else if (dbase == 1) q = (NN - 1) - t;
                else if (dbase == 2) q = (t & (HH - 1)) * WW + (t >> 5);
                else q = perm3[t];
                float w = ldf(aux0, dbase, fin);
                ((float*)out0)[((size_t)(b2 * NN + q)) * 1024 + col] += w * v;
            } else {
                float g = aux1[row >> 10];
                float res = ldf(aux0, oi, fin) + g * v;
                if (fin) ((float*)out0)[oi] = res;
                else ((u16*)out0)[oi] = f2bf(res);
            }
        }
    }
}

// ---------------- depthwise causal conv (k=4) + SiLU ------------------------
__global__ __launch_bounds__(256) void conv_silu(const u16* __restrict__ xi,
                                                 const void* __restrict__ cw,
                                                 u16* __restrict__ xc,
                                                 const int* __restrict__ flags) {
    int fin = flags[0];
    int idx = blockIdx.x * 256 + threadIdx.x;
    int e = idx & 1023;
    int row = idx >> 10;
    int t = row & 1023;
    float acc = 0.f;
#pragma unroll
    for (int k = 0; k < 4; k++) {
        int tt = t - 3 + k;
        if (tt >= 0) acc += ldf(cw, (size_t)e * 4 + k, fin) *
                            bf2f(xi[(size_t)(row - 3 + k) * 1024 + e]);
    }
    xc[idx] = f2bf(acc * sigmoidf_(acc));
}

// ---------------- chunked parallel scan -------------------------------------
// PASS 1: run each chunk from h=0; store chunk-end h and sum(dt).
// PASS 3: run each chunk from corrected incoming h (left in hend by combine);
//         emit yz = sum(h) * silu(z) in-place over xc.
// grid per direction: (ec 4) x (chunk 16) x (b 8) = 512 blocks x 256 threads.
template <int PASS>
__global__ __launch_bounds__(256) void scan_chunk(const float* __restrict__ dtbc,
                                                  u16* __restrict__ xcyz,
                                                  const u16* __restrict__ zb,
                                                  const void* __restrict__ A_log,
                                                  const void* __restrict__ W_dt,
                                                  const void* __restrict__ b_dt,
                                                  const int* __restrict__ flags,
                                                  float* __restrict__ hend,
                                                  float* __restrict__ dtsum) {
    int fin = flags[0];
    int bid = blockIdx.x;
    int ec = bid & 3, c = (bid >> 2) & 15, b = bid >> 6;
    int e = ec * 256 + threadIdx.x;
    __shared__ float sdt[CLEN][32];
    {
        const float* src = dtbc + ((size_t)b * 1024 + c * CLEN) * 64;
        for (int sI = (int)threadIdx.x; sI < CLEN * 8; sI += 256) {
            int t = sI >> 3, f = sI & 7;
            *(float4*)&sdt[t][f * 4] = *(const float4*)(src + (size_t)t * 64 + f * 4);
        }
    }
    float Ae[16], wdt[16];
#pragma unroll
    for (int s = 0; s < 16; s++) Ae[s] = -__expf(ldf(A_log, (size_t)e * 16 + s, fin));
#pragma unroll
    for (int s = 0; s < 16; s++) wdt[s] = ldf(W_dt, (size_t)s * 1024 + e, fin);
    float bd = ldf(b_dt, e, fin);
    float h[16];
    if (PASS == 1) {
#pragma unroll
        for (int s = 0; s < 16; s++) h[s] = 0.f;
    } else {
#pragma unroll
        for (int s = 0; s < 16; s++)
            h[s] = hend[(((size_t)(b * NCHUNK + c)) * 16 + s) * 1024 + e];
    }
    __syncthreads();
    float ds = 0.f;
    size_t rowbase = (size_t)b * 1024 + c * CLEN;
    for (int t = 0; t < CLEN; t++) {
        float4 d0 = *(const float4*)&sdt[t][0];
        float4 d1 = *(const float4*)&sdt[t][4];
        float4 d2 = *(const float4*)&sdt[t][8];
        float4 d3 = *(const float4*)&sdt[t][12];
        float xp = bd;
        xp += d0.x * wdt[0] + d0.y * wdt[1] + d0.z * wdt[2] + d0.w * wdt[3];
        xp += d1.x * wdt[4] + d1.y * wdt[5] + d1.z * wdt[6] + d1.w * wdt[7];
        xp += d2.x * wdt[8] + d2.y * wdt[9] + d2.z * wdt[10] + d2.w * wdt[11];
        xp += d3.x * wdt[12] + d3.y * wdt[13] + d3.z * wdt[14] + d3.w * wdt[15];
        float dtv = (xp > 15.f) ? xp : log1pf(__expf(xp));
        float4 b0 = *(const float4*)&sdt[t][16];
        float4 b1 = *(const float4*)&sdt[t][20];
        float4 b2 = *(const float4*)&sdt[t][24];
        float4 b3 = *(const float4*)&sdt[t][28];
        float bc[16] = {b0.x, b0.y, b0.z, b0.w, b1.x, b1.y, b1.z, b1.w,
                        b2.x, b2.y, b2.z, b2.w, b3.x, b3.y, b3.z, b3.w};
        size_t ix = (rowbase + t) * 1024 + e;
        float xv = bf2f(xcyz[ix]);
        float acc = 0.f;
#pragma unroll
        for (int s = 0; s < 16; s++) {
            h[s] = h[s] * __expf(Ae[s] * dtv) + bc[s] * xv;
            acc += h[s];
        }
        if (PASS == 1) ds += dtv;
        if (PASS == 3) {
            float zv = bf2f(zb[ix]);
            xcyz[ix] = f2bf(acc * (zv * sigmoidf_(zv)));
        }
    }
    if (PASS == 1) {
#pragma unroll
        for (int s = 0; s < 16; s++)
            hend[(((size_t)(b * NCHUNK + c)) * 16 + s) * 1024 + e] = h[s];
        dtsum[((size_t)(b * NCHUNK + c)) * 1024 + e] = ds;
    }
}

// combine chunk states sequentially; leaves incoming state for chunk c in slot c
__global__ __launch_bounds__(256) void scan_combine(float* __restrict__ hend,
                                                    const float* __restrict__ dtsum,
                                                    const void* __restrict__ A_log,
                                                    const int* __restrict__ flags) {
    int fin = flags[0];
    int b = blockIdx.x >> 2;
    int e = (blockIdx.x & 3) * 256 + threadIdx.x;
    float Ae[16];
#pragma unroll
    for (int s = 0; s < 16; s++) Ae[s] = -__expf(ldf(A_log, (size_t)e * 16 + s, fin));
    float H[16];
#pragma unroll
    for (int s = 0; s < 16; s++) H[s] = 0.f;
    for (int c = 0; c < NCHUNK; c++) {
        float ds = dtsum[((size_t)(b * NCHUNK + c)) * 1024 + e];
#pragma unroll
        for (int s = 0; s < 16; s++) {
            size_t idx = (((size_t)(b * NCHUNK + c)) * 16 + s) * 1024 + e;
            float loc = hend[idx];
            float nh = loc + __expf(Ae[s] * ds) * H[s];
            hend[idx] = H[s];
            H[s] = nh;
        }
    }
}

// ---------------- LayerNorm over fused fp32 accumulator ---------------------
__global__ __launch_bounds__(256) void ln_kernel(const float* __restrict__ facc,
                                                 const void* __restrict__ ln_g,
                                                 const void* __restrict__ ln_b,
                                                 const int* __restrict__ flags,
                                                 u16* __restrict__ fn) {
    int fin = flags[0];
    size_t base = (size_t)blockIdx.x * 1024;
    float v[4];
    float sum = 0.f, sq = 0.f;
#pragma unroll
    for (int k = 0; k < 4; k++) {
        int e = threadIdx.x + k * 256;
        float f = facc[base + e];
        v[k] = f;
        sum += f;
        sq += f * f;
    }
    __shared__ float r1[256], r2[256];
    r1[threadIdx.x] = sum;
    r2[threadIdx.x] = sq;
    __syncthreads();
    for (int s = 128; s > 0; s >>= 1) {
        if (threadIdx.x < s) {
            r1[threadIdx.x] += r1[threadIdx.x + s];
            r2[threadIdx.x] += r2[threadIdx.x + s];
        }
        __syncthreads();
    }
    float mu = r1[0] * (1.f / 1024.f);
    float var = r2[0] * (1.f / 1024.f) - mu * mu;
    float rs = rsqrtf(var + 1e-5f);
#pragma unroll
    for (int k = 0; k < 4; k++) {
        int e = threadIdx.x + k * 256;
        fn[base + e] = f2bf((v[k] - mu) * rs * ldf(ln_g, e, fin) + ldf(ln_b, e, fin));
    }
}

// ---------------- gate: partial column sums + final matvec ------------------
__global__ __launch_bounds__(256) void gate_partial(const u16* __restrict__ vfb,
                                                    float* __restrict__ meanv) {
    int b = blockIdx.x >> 4, tc = blockIdx.x & 15;   // 16 chunks of 64 rows
    float s[4] = {0.f, 0.f, 0.f, 0.f};
    const u16* base = vfb + ((size_t)b * 1024 + tc * 64) * 1024;
    for (int t = 0; t < 64; t++) {
#pragma unroll
        for (int k = 0; k < 4; k++)
            s[k] += bf2f(base[(size_t)t * 1024 + threadIdx.x + k * 256]);
    }
#pragma unroll
    for (int k = 0; k < 4; k++)
        atomicAdd(&meanv[b * 1024 + threadIdx.x + k * 256], s[k]);
}

__global__ __launch_bounds__(1024) void gate_final(const float* __restrict__ meanv,
                                                   const void* __restrict__ Wg1,
                                                   const void* __restrict__ Wg2,
                                                   const int* __restrict__ flags,
                                                   float* __restrict__ g) {
    int fin = flags[0];
    int b = blockIdx.x;
    __shared__ float mv[1024];
    __shared__ float part[1024];
    __shared__ float red[256];
    mv[threadIdx.x] = meanv[b * 1024 + threadIdx.x] * (1.f / 1024.f);
    __syncthreads();
    int j = threadIdx.x & 255, kc = threadIdx.x >> 8;
    float a = 0.f;
    for (int k = kc * 256; k < kc * 256 + 256; k++)
        a += mv[k] * ldf(Wg1, (size_t)k * 256 + j, fin);
    part[threadIdx.x] = a;
    __syncthreads();
    if (threadIdx.x < 256) {
        float ssum = part[j] + part[j + 256] + part[j + 512] + part[j + 768];
        float si = ssum * sigmoidf_(ssum);
        red[j] = si * ldf(Wg2, j, fin);
    }
    __syncthreads();
    for (int st = 128; st > 0; st >>= 1) {
        if (threadIdx.x < st) red[threadIdx.x] += red[threadIdx.x + st];
        __syncthreads();
    }
    if (threadIdx.x == 0) g[b] = sigmoidf_(red[0]);
}

// ---------------- launch ----------------------------------------------------
extern "C" void kernel_launch(void* const* d_in, const int* in_sizes, int n_in,
                              void* d_out, int out_size, void* d_ws, size_t ws_size,
                              hipStream_t stream) {
    const void* vf_raw  = d_in[0];
    const void* W_input = d_in[1];
    const void* W_in    = d_in[2];
    const void* conv_w  = d_in[3];
    const void* W_xproj = d_in[4];
    const void* W_dt    = d_in[5];
    const void* b_dt    = d_in[6];
    const void* A_log   = d_in[7];
    const void* W_outm  = d_in[8];
    const void* dir_w   = d_in[9];
    const void* ln_g    = d_in[10];
    const void* ln_b    = d_in[11];
    const void* W_outpj = d_in[12];
    const void* Wg1     = d_in[13];
    const void* Wg2     = d_in[14];

    char* ws = (char*)d_ws;
    size_t off = 0;
    auto alloc = [&](size_t bytes) -> void* {
        void* p = ws + off;
        off = (off + bytes + 255) & ~(size_t)255;
        return p;
    };
    int*   flags = (int*)alloc(256);
    int*   perm3 = (int*)alloc(NN * 4);
    int*   inv3  = (int*)alloc(NN * 4);
    float* meanv = (float*)alloc(8 * 1024 * 4);
    float* gbuf  = (float*)alloc(64);
    u16*   WtI   = (u16*)alloc((size_t)1024 * 1024 * 2);
    u16*   WtIn  = (u16*)alloc((size_t)2048 * 1024 * 2);
    u16*   WtXp  = (u16*)alloc((size_t)64 * 1024 * 2);
    u16*   WtOm  = (u16*)alloc((size_t)1024 * 1024 * 2);
    u16*   WtOp  = (u16*)alloc((size_t)1024 * 1024 * 2);
    u16*   vfb   = (u16*)alloc((size_t)M1 * 1024 * 2);   // vf bf16; dead after
                                                         // stage2+gate -> scan scratch
    u16*   xbuf  = (u16*)alloc((size_t)M1 * 1024 * 2);
    float* facc  = (float*)alloc((size_t)M1 * 1024 * 4);
    u16*   xi    = (u16*)alloc((size_t)M1 * 1024 * 2);   // later: fn
    u16*   zb    = (u16*)alloc((size_t)M1 * 1024 * 2);
    u16*   xc    = (u16*)alloc((size_t)M1 * 1024 * 2);   // becomes yz in-place
    float* dtbc  = (float*)alloc((size_t)M1 * 64 * 4);
    // peak ~124.5 MB (same envelope as the passing round-2 layout)
    float* hend  = (float*)vfb;                          // 8 MB (8*16*16*1024 f32)
    float* dtsum = hend + (size_t)8 * NCHUNK * 16 * 1024; // 512 KB

    detect_dtype<<<1, 64, 0, stream>>>((const u16*)vf_raw, flags);
    convert_bf<<<(M1 * 1024) / 256, 256, 0, stream>>>(vf_raw, vfb, flags, M1 * 1024);
    diag_perm_init<<<4, 256, 0, stream>>>(perm3, inv3);
    transpose_pad<<<dim3(32, 32), 256, 0, stream>>>(W_input, WtI, 1024, 1024, flags);
    transpose_pad<<<dim3(32, 64), 256, 0, stream>>>(W_in, WtIn, 1024, 2048, flags);
    transpose_pad<<<dim3(32, 2), 256, 0, stream>>>(W_xproj, WtXp, 1024, 32, flags);
    transpose_pad<<<dim3(32, 32), 256, 0, stream>>>(W_outm, WtOm, 1024, 1024, flags);
    transpose_pad<<<dim3(32, 32), 256, 0, stream>>>(W_outpj, WtOp, 1024, 1024, flags);
    zero_f32<<<(M1 * 1024) / 256, 256, 0, stream>>>(facc, M1 * 1024);
    zero_f32<<<32, 256, 0, stream>>>(meanv, 8 * 1024);

    // gate (uses vfb; must finish before scan scratch aliases it — stream-ordered)
    gate_partial<<<128, 256, 0, stream>>>(vfb, meanv);
    gate_final<<<8, 1024, 0, stream>>>(meanv, Wg1, Wg2, flags, gbuf);

    // x = vf @ W_input
    gemm_bt<0, 0><<<dim3(M1 / 64, 16), 256, 0, stream>>>(
        vfb, WtI, xbuf, nullptr, M1, 1024, 1024, perm3, flags, 0, nullptr, nullptr);

    for (int d = 0; d < 4; d++) {
        gemm_bt<1, 1><<<dim3(M1 / 64, 32), 256, 0, stream>>>(
            xbuf, WtIn, xi, zb, M1, 2048, 1024, perm3, flags, d, nullptr, nullptr);
        conv_silu<<<M1 * 4, 256, 0, stream>>>(xi, conv_w, xc, flags);
        gemm_bt<0, 2><<<dim3(M1 / 64, 1), 256, 0, stream>>>(
            xc, WtXp, dtbc, nullptr, M1, 64, 1024, perm3, flags, d, nullptr, nullptr);
        scan_chunk<1><<<512, 256, 0, stream>>>(dtbc, xc, zb, A_log, W_dt, b_dt,
                                               flags, hend, dtsum);
        scan_combine<<<32, 256, 0, stream>>>(hend, dtsum, A_log, flags);
        scan_chunk<3><<<512, 256, 0, stream>>>(dtbc, xc, zb, A_log, W_dt, b_dt,
                                               flags, hend, dtsum);
        gemm_bt<0, 3><<<dim3(M1 / 64, 16), 256, 0, stream>>>(
            xc, WtOm, facc, nullptr, M1, 1024, 1024, perm3, flags, d, dir_w, nullptr);
    }

    u16* fn = xi;
    ln_kernel<<<M1, 256, 0, stream>>>(facc, ln_g, ln_b, flags, fn);
    gemm_bt<0, 4><<<dim3(M1 / 64, 16), 256, 0, stream>>>(
        fn, WtOp, d_out, nullptr, M1, 1024, 1024, perm3, flags, 0, vf_raw, gbuf);
}

// Round 4
// 1528.337 us; speedup vs baseline: 3.2817x; 1.0793x over previous
//
#include <hip/hip_runtime.h>

typedef unsigned short u16;
typedef unsigned int u32;
typedef short v8s __attribute__((ext_vector_type(8)));
typedef float v4f __attribute__((ext_vector_type(4)));

#define B_SZ 8
#define HH 32
#define WW 32
#define NN 1024          // H*W
#define M1 (B_SZ * NN)   // 8192 rows (one direction)
#define NCHUNK 16
#define CLEN 64          // NCHUNK*CLEN = 1024

__device__ __forceinline__ float bf2f(u16 u) {
    u32 x = ((u32)u) << 16;
    return __builtin_bit_cast(float, x);
}
__device__ __forceinline__ u16 f2bf(float f) {
    u32 x = __builtin_bit_cast(u32, f);
    x = x + 0x7fffu + ((x >> 16) & 1u);
    return (u16)(x >> 16);
}
__device__ __forceinline__ float sigmoidf_(float x) { return 1.f / (1.f + __expf(-x)); }
__device__ __forceinline__ float ldf(const void* p, size_t i, int fin) {
    return fin ? ((const float*)p)[i] : bf2f(((const u16*)p)[i]);
}
__device__ __forceinline__ u16 ldbf(const void* p, size_t i, int fin) {
    return fin ? f2bf(((const float*)p)[i]) : ((const u16*)p)[i];
}
// async global->LDS, 16B per lane; LDS dest = wave-uniform base + lane*16
__device__ __forceinline__ void gload_lds16(const u16* g, u16* l) {
    __builtin_amdgcn_global_load_lds(
        (const __attribute__((address_space(1))) unsigned int*)g,
        (__attribute__((address_space(3))) unsigned int*)l, 16, 0, 0);
}
__device__ __forceinline__ int dirmap(int d, int t, const int* __restrict__ perm3) {
    if (d == 0) return t;
    if (d == 1) return (NN - 1) - t;
    if (d == 2) return (t & (HH - 1)) * WW + (t >> 5);
    return perm3[t];
}

// ---------------- input dtype sniffer ---------------------------------------
__global__ void detect_dtype(const u16* __restrict__ raw, int* __restrict__ flags) {
    if (threadIdx.x == 0 && blockIdx.x == 0) {
        int ok = 0;
        for (int i = 0; i < 512; i++) {
            int e = (raw[i] >> 7) & 0xFF;
            ok += (e >= 100 && e <= 140) ? 1 : 0;
        }
        flags[0] = (ok < 460) ? 1 : 0;
    }
}

__global__ __launch_bounds__(256) void convert_bf(const void* __restrict__ src,
                                                  u16* __restrict__ dst,
                                                  const int* __restrict__ flags, int n) {
    int fin = flags[0];
    int i = blockIdx.x * 256 + threadIdx.x;
    if (i < n) dst[i] = ldbf(src, (size_t)i, fin);
}

__global__ __launch_bounds__(256) void zero_f32(float* __restrict__ p, int n) {
    int i = blockIdx.x * 256 + threadIdx.x;
    if (i < n) p[i] = 0.f;
}

// ---------------- diagonal permutation init ---------------------------------
__global__ void diag_perm_init(int* __restrict__ perm, int* __restrict__ inv) {
    int t = blockIdx.x * blockDim.x + threadIdx.x;
    if (t >= NN) return;
    int i = t / WW, j = t % WW;
    int off = j - i;
    int start = 0;
    for (int o = -(HH - 1); o < off; ++o) {
        int lo = (0 > -o) ? 0 : -o;
        int hi = (HH - 1 < WW - 1 - o) ? (HH - 1) : (WW - 1 - o);
        start += (hi - lo + 1);
    }
    int lo0 = (0 > -off) ? 0 : -off;
    int r = start + (i - lo0);
    perm[r] = t;
    inv[t] = r;
}

// ---------------- weight transpose+pad: src (K x Nsrc) -> dst (Npad x K) ----
__global__ __launch_bounds__(256) void transpose_pad(const void* __restrict__ src,
                                                     u16* __restrict__ dst,
                                                     int K, int Nsrc,
                                                     const int* __restrict__ flags) {
    int fin = flags[0];
    __shared__ u16 tile[32][33];
    int k0 = blockIdx.x * 32, n0 = blockIdx.y * 32;
    int tx = threadIdx.x & 31, ty = threadIdx.x >> 5;
#pragma unroll
    for (int i = 0; i < 4; i++) {
        int k = k0 + ty + i * 8, n = n0 + tx;
        tile[ty + i * 8][tx] = (n < Nsrc) ? ldbf(src, (size_t)k * Nsrc + n, fin) : (u16)0;
    }
    __syncthreads();
#pragma unroll
    for (int i = 0; i < 4; i++) {
        int n = n0 + ty + i * 8, k = k0 + tx;
        dst[(size_t)n * K + k] = tile[tx][ty + i * 8];
    }
}

// ---------------- 128x128 MFMA GEMM (global_load_lds staging) ---------------
// C(MxN) = A(MxK) * Bt(NxK)^T. 256 thr = 4 waves, wave does 64x64 (4x4 MFMA).
// AM: 0 = plain rows; 1 = direction gather (dir=dbase, lda=1024)
// EM: 0 bf16; 1 split xz->xi,z (N=2048); 3 scatter-acc facc (aux0=dir_w);
//     4 final out = vf + g*acc (aux0=vf raw, aux1=g)
template <int AM, int EM>
__global__ __launch_bounds__(256) void gemm128(const u16* __restrict__ A,
                                               const u16* __restrict__ Bt,
                                               void* __restrict__ out0,
                                               void* __restrict__ out1,
                                               int M, int N, int K,
                                               const int* __restrict__ perm3,
                                               const int* __restrict__ flags,
                                               int dbase,
                                               const void* __restrict__ aux0,
                                               const float* __restrict__ aux1) {
    int fin = flags[0];
    __shared__ __align__(16) u16 As[128][32];
    __shared__ __align__(16) u16 Bs[128][32];
    int tid = threadIdx.x;
    int wave = tid >> 6, lane = tid & 63, quad = lane >> 4, l16 = lane & 15;
    int wm = wave >> 1, wn = wave & 1;
    int m0 = blockIdx.x * 128, n0 = blockIdx.y * 128;
    int r = tid >> 2, seg = (tid & 3) * 8;   // staging: row r / 64+r, 8-elem seg

    const u16 *rA0, *rA1;
    if (AM == 1) {
        int ra = m0 + r, rb = m0 + 64 + r;
        int b = (ra >> 10) & 7;  // same b for ra,rb (m0%128==0)
        rA0 = A + ((size_t)(b * NN + dirmap(dbase, ra & 1023, perm3))) * 1024;
        rA1 = A + ((size_t)(b * NN + dirmap(dbase, rb & 1023, perm3))) * 1024;
    } else {
        rA0 = A + (size_t)(m0 + r) * K;
        rA1 = A + (size_t)(m0 + 64 + r) * K;
    }
    const u16* rB0 = Bt + (size_t)(n0 + r) * K;
    const u16* rB1 = Bt + (size_t)(n0 + 64 + r) * K;

    v4f acc[4][4];
#pragma unroll
    for (int i = 0; i < 4; i++)
#pragma unroll
        for (int j = 0; j < 4; j++) acc[i][j] = (v4f){0.f, 0.f, 0.f, 0.f};

    for (int k0 = 0; k0 < K; k0 += 32) {
        gload_lds16(rA0 + k0 + seg, &As[r][seg]);
        gload_lds16(rA1 + k0 + seg, &As[64 + r][seg]);
        gload_lds16(rB0 + k0 + seg, &Bs[r][seg]);
        gload_lds16(rB1 + k0 + seg, &Bs[64 + r][seg]);
        __syncthreads();
        v8s af[4], bf[4];
#pragma unroll
        for (int i = 0; i < 4; i++)
            af[i] = *(const v8s*)&As[wm * 64 + i * 16 + l16][quad * 8];
#pragma unroll
        for (int j = 0; j < 4; j++)
            bf[j] = *(const v8s*)&Bs[wn * 64 + j * 16 + l16][quad * 8];
#pragma unroll
        for (int i = 0; i < 4; i++)
#pragma unroll
            for (int j = 0; j < 4; j++)
                acc[i][j] = __builtin_amdgcn_mfma_f32_16x16x32_bf16(af[i], bf[j],
                                                                    acc[i][j], 0, 0, 0);
        __syncthreads();
    }

#pragma unroll
    for (int i = 0; i < 4; i++) {
#pragma unroll
        for (int j = 0; j < 4; j++) {
#pragma unroll
            for (int rr = 0; rr < 4; rr++) {
                int row = m0 + wm * 64 + i * 16 + quad * 4 + rr;
                int col = n0 + wn * 64 + j * 16 + l16;
                float v = acc[i][j][rr];
                size_t oi = (size_t)row * N + col;
                if (EM == 0) {
                    ((u16*)out0)[oi] = f2bf(v);
                } else if (EM == 1) {
                    if (col < 1024) ((u16*)out0)[(size_t)row * 1024 + col] = f2bf(v);
                    else ((u16*)out1)[(size_t)row * 1024 + (col - 1024)] = f2bf(v);
                } else if (EM == 3) {
                    int b2 = row >> 10, t = row & 1023;
                    int q = dirmap(dbase, t, perm3);
                    float w = ldf(aux0, dbase, fin);
                    ((float*)out0)[((size_t)(b2 * NN + q)) * 1024 + col] += w * v;
                } else {
                    float g = aux1[row >> 10];
                    float res = ldf(aux0, oi, fin) + g * v;
                    if (fin) ((float*)out0)[oi] = res;
                    else ((u16*)out0)[oi] = f2bf(res);
                }
            }
        }
    }
}

// ---------------- 64-tile GEMM (kept for dtbc: N=64, fp32 out) --------------
__global__ __launch_bounds__(256) void gemm_dtbc(const u16* __restrict__ A,
                                                 const u16* __restrict__ Bt,
                                                 float* __restrict__ out0,
                                                 int M, int N, int K) {
    __shared__ u16 As[64][32];
    __shared__ u16 Bs[64][32];
    int tid = threadIdx.x;
    int wave = tid >> 6, lane = tid & 63, quad = lane >> 4, l16 = lane & 15;
    int m0 = blockIdx.x * 64, n0 = blockIdx.y * 64;
    int lr = tid >> 2, seg = (tid & 3) * 8;
    const u16* arow = A + (size_t)(m0 + lr) * K;
    const u16* brow = Bt + (size_t)(n0 + lr) * K;
    v4f acc[4];
#pragma unroll
    for (int j = 0; j < 4; j++) acc[j] = (v4f){0.f, 0.f, 0.f, 0.f};
    for (int k0 = 0; k0 < K; k0 += 32) {
        uint4 av = *(const uint4*)(arow + k0 + seg);
        uint4 bv = *(const uint4*)(brow + k0 + seg);
        *(uint4*)&As[lr][seg] = av;
        *(uint4*)&Bs[lr][seg] = bv;
        __syncthreads();
        v8s af = *(const v8s*)&As[wave * 16 + l16][quad * 8];
#pragma unroll
        for (int j = 0; j < 4; j++) {
            v8s bf = *(const v8s*)&Bs[j * 16 + l16][quad * 8];
            acc[j] = __builtin_amdgcn_mfma_f32_16x16x32_bf16(af, bf, acc[j], 0, 0, 0);
        }
        __syncthreads();
    }
#pragma unroll
    for (int j = 0; j < 4; j++)
#pragma unroll
        for (int rr = 0; rr < 4; rr++) {
            int row = m0 + wave * 16 + quad * 4 + rr;
            int col = n0 + j * 16 + l16;
            out0[(size_t)row * N + col] = acc[j][rr];
        }
}

// ---------------- depthwise causal conv (k=4) + SiLU ------------------------
__global__ __launch_bounds__(256) void conv_silu(const u16* __restrict__ xi,
                                                 const void* __restrict__ cw,
                                                 u16* __restrict__ xc,
                                                 const int* __restrict__ flags) {
    int fin = flags[0];
    int idx = blockIdx.x * 256 + threadIdx.x;
    int e = idx & 1023;
    int row = idx >> 10;
    int t = row & 1023;
    float acc = 0.f;
#pragma unroll
    for (int k = 0; k < 4; k++) {
        int tt = t - 3 + k;
        if (tt >= 0) acc += ldf(cw, (size_t)e * 4 + k, fin) *
                            bf2f(xi[(size_t)(row - 3 + k) * 1024 + e]);
    }
    xc[idx] = f2bf(acc * sigmoidf_(acc));
}

// ---------------- chunked parallel scan -------------------------------------
template <int PASS>
__global__ __launch_bounds__(256) void scan_chunk(const float* __restrict__ dtbc,
                                                  u16* __restrict__ xcyz,
                                                  const u16* __restrict__ zb,
                                                  const void* __restrict__ A_log,
                                                  const void* __restrict__ W_dt,
                                                  const void* __restrict__ b_dt,
                                                  const int* __restrict__ flags,
                                                  float* __restrict__ hend,
                                                  float* __restrict__ dtsum) {
    int fin = flags[0];
    int bid = blockIdx.x;
    int ec = bid & 3, c = (bid >> 2) & 15, b = bid >> 6;
    int e = ec * 256 + threadIdx.x;
    __shared__ float sdt[CLEN][32];
    {
        const float* src = dtbc + ((size_t)b * 1024 + c * CLEN) * 64;
        for (int sI = (int)threadIdx.x; sI < CLEN * 8; sI += 256) {
            int t = sI >> 3, f = sI & 7;
            *(float4*)&sdt[t][f * 4] = *(const float4*)(src + (size_t)t * 64 + f * 4);
        }
    }
    float Ae[16], wdt[16];
#pragma unroll
    for (int s = 0; s < 16; s++) Ae[s] = -__expf(ldf(A_log, (size_t)e * 16 + s, fin));
#pragma unroll
    for (int s = 0; s < 16; s++) wdt[s] = ldf(W_dt, (size_t)s * 1024 + e, fin);
    float bd = ldf(b_dt, e, fin);
    float h[16];
    if (PASS == 1) {
#pragma unroll
        for (int s = 0; s < 16; s++) h[s] = 0.f;
    } else {
#pragma unroll
        for (int s = 0; s < 16; s++)
            h[s] = hend[(((size_t)(b * NCHUNK + c)) * 16 + s) * 1024 + e];
    }
    __syncthreads();
    float ds = 0.f;
    size_t rowbase = (size_t)b * 1024 + c * CLEN;
    for (int t = 0; t < CLEN; t++) {
        float4 d0 = *(const float4*)&sdt[t][0];
        float4 d1 = *(const float4*)&sdt[t][4];
        float4 d2 = *(const float4*)&sdt[t][8];
        float4 d3 = *(const float4*)&sdt[t][12];
        float xp = bd;
        xp += d0.x * wdt[0] + d0.y * wdt[1] + d0.z * wdt[2] + d0.w * wdt[3];
        xp += d1.x * wdt[4] + d1.y * wdt[5] + d1.z * wdt[6] + d1.w * wdt[7];
        xp += d2.x * wdt[8] + d2.y * wdt[9] + d2.z * wdt[10] + d2.w * wdt[11];
        xp += d3.x * wdt[12] + d3.y * wdt[13] + d3.z * wdt[14] + d3.w * wdt[15];
        float dtv = (xp > 15.f) ? xp : log1pf(__expf(xp));
        float4 b0 = *(const float4*)&sdt[t][16];
        float4 b1 = *(const float4*)&sdt[t][20];
        float4 b2 = *(const float4*)&sdt[t][24];
        float4 b3 = *(const float4*)&sdt[t][28];
        float bc[16] = {b0.x, b0.y, b0.z, b0.w, b1.x, b1.y, b1.z, b1.w,
                        b2.x, b2.y, b2.z, b2.w, b3.x, b3.y, b3.z, b3.w};
        size_t ix = (rowbase + t) * 1024 + e;
        float xv = bf2f(xcyz[ix]);
        float acc = 0.f;
#pragma unroll
        for (int s = 0; s < 16; s++) {
            h[s] = h[s] * __expf(Ae[s] * dtv) + bc[s] * xv;
            acc += h[s];
        }
        if (PASS == 1) ds += dtv;
        if (PASS == 3) {
            float zv = bf2f(zb[ix]);
            xcyz[ix] = f2bf(acc * (zv * sigmoidf_(zv)));
        }
    }
    if (PASS == 1) {
#pragma unroll
        for (int s = 0; s < 16; s++)
            hend[(((size_t)(b * NCHUNK + c)) * 16 + s) * 1024 + e] = h[s];
        dtsum[((size_t)(b * NCHUNK + c)) * 1024 + e] = ds;
    }
}

__global__ __launch_bounds__(256) void scan_combine(float* __restrict__ hend,
                                                    const float* __restrict__ dtsum,
                                                    const void* __restrict__ A_log,
                                                    const int* __restrict__ flags) {
    int fin = flags[0];
    int b = blockIdx.x >> 2;
    int e = (blockIdx.x & 3) * 256 + threadIdx.x;
    float Ae[16];
#pragma unroll
    for (int s = 0; s < 16; s++) Ae[s] = -__expf(ldf(A_log, (size_t)e * 16 + s, fin));
    float H[16];
#pragma unroll
    for (int s = 0; s < 16; s++) H[s] = 0.f;
    for (int c = 0; c < NCHUNK; c++) {
        float ds = dtsum[((size_t)(b * NCHUNK + c)) * 1024 + e];
#pragma unroll
        for (int s = 0; s < 16; s++) {
            size_t idx = (((size_t)(b * NCHUNK + c)) * 16 + s) * 1024 + e;
            float loc = hend[idx];
            float nh = loc + __expf(Ae[s] * ds) * H[s];
            hend[idx] = H[s];
            H[s] = nh;
        }
    }
}

// ---------------- LayerNorm over fused fp32 accumulator ---------------------
__global__ __launch_bounds__(256) void ln_kernel(const float* __restrict__ facc,
                                                 const void* __restrict__ ln_g,
                                                 const void* __restrict__ ln_b,
                                                 const int* __restrict__ flags,
                                                 u16* __restrict__ fn) {
    int fin = flags[0];
    size_t base = (size_t)blockIdx.x * 1024;
    float v[4];
    float sum = 0.f, sq = 0.f;
#pragma unroll
    for (int k = 0; k < 4; k++) {
        int e = threadIdx.x + k * 256;
        float f = facc[base + e];
        v[k] = f;
        sum += f;
        sq += f * f;
    }
    __shared__ float r1[256], r2[256];
    r1[threadIdx.x] = sum;
    r2[threadIdx.x] = sq;
    __syncthreads();
    for (int s = 128; s > 0; s >>= 1) {
        if (threadIdx.x < s) {
            r1[threadIdx.x] += r1[threadIdx.x + s];
            r2[threadIdx.x] += r2[threadIdx.x + s];
        }
        __syncthreads();
    }
    float mu = r1[0] * (1.f / 1024.f);
    float var = r2[0] * (1.f / 1024.f) - mu * mu;
    float rs = rsqrtf(var + 1e-5f);
#pragma unroll
    for (int k = 0; k < 4; k++) {
        int e = threadIdx.x + k * 256;
        fn[base + e] = f2bf((v[k] - mu) * rs * ldf(ln_g, e, fin) + ldf(ln_b, e, fin));
    }
}

// ---------------- gate: partial col sums -> shared matvec -> finisher -------
__global__ __launch_bounds__(256) void gate_partial(const u16* __restrict__ vfb,
                                                    float* __restrict__ meanv) {
    int b = blockIdx.x >> 4, tc = blockIdx.x & 15;
    float s[4] = {0.f, 0.f, 0.f, 0.f};
    const u16* base = vfb + ((size_t)b * 1024 + tc * 64) * 1024;
    for (int t = 0; t < 64; t++) {
#pragma unroll
        for (int k = 0; k < 4; k++)
            s[k] += bf2f(base[(size_t)t * 1024 + threadIdx.x + k * 256]);
    }
#pragma unroll
    for (int k = 0; k < 4; k++)
        atomicAdd(&meanv[b * 1024 + threadIdx.x + k * 256], s[k]);
}

// Wg1 read exactly once; each weight reused for all 8 batches.
// grid 32 (k-slices of 32), 256 threads (j).
__global__ __launch_bounds__(256) void gate_mv(const float* __restrict__ meanv,
                                               const void* __restrict__ Wg1,
                                               const int* __restrict__ flags,
                                               float* __restrict__ gpart) {
    int fin = flags[0];
    int kc = blockIdx.x, j = threadIdx.x;
    __shared__ float mv[8][32];
    if (threadIdx.x < 8 * 32) {
        int b = threadIdx.x >> 5, kk = threadIdx.x & 31;
        mv[b][kk] = meanv[b * 1024 + kc * 32 + kk] * (1.f / 1024.f);
    }
    __syncthreads();
    float acc[8];
#pragma unroll
    for (int b = 0; b < 8; b++) acc[b] = 0.f;
    for (int kk = 0; kk < 32; kk++) {
        float w = ldf(Wg1, (size_t)(kc * 32 + kk) * 256 + j, fin);
#pragma unroll
        for (int b = 0; b < 8; b++) acc[b] += mv[b][kk] * w;
    }
#pragma unroll
    for (int b = 0; b < 8; b++) atomicAdd(&gpart[b * 256 + j], acc[b]);
}

__global__ __launch_bounds__(256) void gate_fin2(const float* __restrict__ gpart,
                                                 const void* __restrict__ Wg2,
                                                 const int* __restrict__ flags,
                                                 float* __restrict__ g) {
    int fin = flags[0];
    int b = blockIdx.x, j = threadIdx.x;
    __shared__ float red[256];
    float a = gpart[b * 256 + j];
    float si = a * sigmoidf_(a);
    red[j] = si * ldf(Wg2, j, fin);
    __syncthreads();
    for (int st = 128; st > 0; st >>= 1) {
        if (j < st) red[j] += red[j + st];
        __syncthreads();
    }
    if (j == 0) g[b] = sigmoidf_(red[0]);
}

// ---------------- launch ----------------------------------------------------
extern "C" void kernel_launch(void* const* d_in, const int* in_sizes, int n_in,
                              void* d_out, int out_size, void* d_ws, size_t ws_size,
                              hipStream_t stream) {
    const void* vf_raw  = d_in[0];
    const void* W_input = d_in[1];
    const void* W_in    = d_in[2];
    const void* conv_w  = d_in[3];
    const void* W_xproj = d_in[4];
    const void* W_dt    = d_in[5];
    const void* b_dt    = d_in[6];
    const void* A_log   = d_in[7];
    const void* W_outm  = d_in[8];
    const void* dir_w   = d_in[9];
    const void* ln_g    = d_in[10];
    const void* ln_b    = d_in[11];
    const void* W_outpj = d_in[12];
    const void* Wg1     = d_in[13];
    const void* Wg2     = d_in[14];

    char* ws = (char*)d_ws;
    size_t off = 0;
    auto alloc = [&](size_t bytes) -> void* {
        void* p = ws + off;
        off = (off + bytes + 255) & ~(size_t)255;
        return p;
    };
    int*   flags = (int*)alloc(256);
    int*   perm3 = (int*)alloc(NN * 4);
    int*   inv3  = (int*)alloc(NN * 4);
    float* meanv = (float*)alloc(8 * 1024 * 4);
    float* gpart = (float*)alloc(8 * 256 * 4);
    float* gbuf  = (float*)alloc(64);
    u16*   WtI   = (u16*)alloc((size_t)1024 * 1024 * 2);
    u16*   WtIn  = (u16*)alloc((size_t)2048 * 1024 * 2);
    u16*   WtXp  = (u16*)alloc((size_t)64 * 1024 * 2);
    u16*   WtOm  = (u16*)alloc((size_t)1024 * 1024 * 2);
    u16*   WtOp  = (u16*)alloc((size_t)1024 * 1024 * 2);
    u16*   vfb   = (u16*)alloc((size_t)M1 * 1024 * 2);   // scan scratch later
    u16*   xbuf  = (u16*)alloc((size_t)M1 * 1024 * 2);
    float* facc  = (float*)alloc((size_t)M1 * 1024 * 4);
    u16*   xi    = (u16*)alloc((size_t)M1 * 1024 * 2);   // later: fn
    u16*   zb    = (u16*)alloc((size_t)M1 * 1024 * 2);
    u16*   xc    = (u16*)alloc((size_t)M1 * 1024 * 2);   // becomes yz in-place
    float* dtbc  = (float*)alloc((size_t)M1 * 64 * 4);
    // peak ~124.5 MB (same envelope as passing rounds 2/3)
    float* hend  = (float*)vfb;                           // 8 MB
    float* dtsum = hend + (size_t)8 * NCHUNK * 16 * 1024; // 512 KB

    detect_dtype<<<1, 64, 0, stream>>>((const u16*)vf_raw, flags);
    convert_bf<<<(M1 * 1024) / 256, 256, 0, stream>>>(vf_raw, vfb, flags, M1 * 1024);
    diag_perm_init<<<4, 256, 0, stream>>>(perm3, inv3);
    transpose_pad<<<dim3(32, 32), 256, 0, stream>>>(W_input, WtI, 1024, 1024, flags);
    transpose_pad<<<dim3(32, 64), 256, 0, stream>>>(W_in, WtIn, 1024, 2048, flags);
    transpose_pad<<<dim3(32, 2), 256, 0, stream>>>(W_xproj, WtXp, 1024, 32, flags);
    transpose_pad<<<dim3(32, 32), 256, 0, stream>>>(W_outm, WtOm, 1024, 1024, flags);
    transpose_pad<<<dim3(32, 32), 256, 0, stream>>>(W_outpj, WtOp, 1024, 1024, flags);
    zero_f32<<<(M1 * 1024) / 256, 256, 0, stream>>>(facc, M1 * 1024);
    zero_f32<<<32, 256, 0, stream>>>(meanv, 8 * 1024);
    zero_f32<<<8, 256, 0, stream>>>(gpart, 8 * 256);

    // gate (uses vfb before scan scratch aliases it — stream-ordered)
    gate_partial<<<128, 256, 0, stream>>>(vfb, meanv);
    gate_mv<<<32, 256, 0, stream>>>(meanv, Wg1, flags, gpart);
    gate_fin2<<<8, 256, 0, stream>>>(gpart, Wg2, flags, gbuf);

    // x = vf @ W_input
    gemm128<0, 0><<<dim3(64, 8), 256, 0, stream>>>(
        vfb, WtI, xbuf, nullptr, M1, 1024, 1024, perm3, flags, 0, nullptr, nullptr);

    for (int d = 0; d < 4; d++) {
        gemm128<1, 1><<<dim3(64, 16), 256, 0, stream>>>(
            xbuf, WtIn, xi, zb, M1, 2048, 1024, perm3, flags, d, nullptr, nullptr);
        conv_silu<<<M1 * 4, 256, 0, stream>>>(xi, conv_w, xc, flags);
        gemm_dtbc<<<dim3(128, 1), 256, 0, stream>>>(xc, WtXp, dtbc, M1, 64, 1024);
        scan_chunk<1><<<512, 256, 0, stream>>>(dtbc, xc, zb, A_log, W_dt, b_dt,
                                               flags, hend, dtsum);
        scan_combine<<<32, 256, 0, stream>>>(hend, dtsum, A_log, flags);
        scan_chunk<3><<<512, 256, 0, stream>>>(dtbc, xc, zb, A_log, W_dt, b_dt,
                                               flags, hend, dtsum);
        gemm128<0, 3><<<dim3(64, 8), 256, 0, stream>>>(
            xc, WtOm, facc, nullptr, M1, 1024, 1024, perm3, flags, d, dir_w, nullptr);
    }

    u16* fn = xi;
    ln_kernel<<<M1, 256, 0, stream>>>(facc, ln_g, ln_b, flags, fn);
    gemm128<0, 4><<<dim3(64, 8), 256, 0, stream>>>(
        fn, WtOp, d_out, nullptr, M1, 1024, 1024, perm3, flags, 0, vf_raw, gbuf);
}

// Round 5
// 1406.319 us; speedup vs baseline: 3.5664x; 1.0868x over previous
//
#include <hip/hip_runtime.h>

typedef unsigned short u16;
typedef unsigned int u32;
typedef short v8s __attribute__((ext_vector_type(8)));
typedef float v4f __attribute__((ext_vector_type(4)));

#define B_SZ 8
#define HH 32
#define WW 32
#define NN 1024          // H*W
#define M1 (B_SZ * NN)   // 8192 rows (one direction)
#define NCHUNK 32
#define CLEN 32          // NCHUNK*CLEN = 1024

__device__ __forceinline__ float bf2f(u16 u) {
    u32 x = ((u32)u) << 16;
    return __builtin_bit_cast(float, x);
}
__device__ __forceinline__ u16 f2bf(float f) {
    u32 x = __builtin_bit_cast(u32, f);
    x = x + 0x7fffu + ((x >> 16) & 1u);
    return (u16)(x >> 16);
}
__device__ __forceinline__ float sigmoidf_(float x) { return 1.f / (1.f + __expf(-x)); }
__device__ __forceinline__ float ldf(const void* p, size_t i, int fin) {
    return fin ? ((const float*)p)[i] : bf2f(((const u16*)p)[i]);
}
__device__ __forceinline__ u16 ldbf(const void* p, size_t i, int fin) {
    return fin ? f2bf(((const float*)p)[i]) : ((const u16*)p)[i];
}
// async global->LDS, 16B per lane; LDS dest = wave-uniform base + lane*16
__device__ __forceinline__ void gload_lds16(const u16* g, u16* l) {
    __builtin_amdgcn_global_load_lds(
        (const __attribute__((address_space(1))) unsigned int*)g,
        (__attribute__((address_space(3))) unsigned int*)l, 16, 0, 0);
}
__device__ __forceinline__ int dirmap(int d, int t, const int* __restrict__ perm3) {
    if (d == 0) return t;
    if (d == 1) return (NN - 1) - t;
    if (d == 2) return (t & (HH - 1)) * WW + (t >> 5);
    return perm3[t];
}

// ---------------- input dtype sniffer ---------------------------------------
__global__ void detect_dtype(const u16* __restrict__ raw, int* __restrict__ flags) {
    if (threadIdx.x == 0 && blockIdx.x == 0) {
        int ok = 0;
        for (int i = 0; i < 512; i++) {
            int e = (raw[i] >> 7) & 0xFF;
            ok += (e >= 100 && e <= 140) ? 1 : 0;
        }
        flags[0] = (ok < 460) ? 1 : 0;
    }
}

__global__ __launch_bounds__(256) void convert_bf(const void* __restrict__ src,
                                                  u16* __restrict__ dst,
                                                  const int* __restrict__ flags, int n) {
    int fin = flags[0];
    int i = blockIdx.x * 256 + threadIdx.x;
    if (i < n) dst[i] = ldbf(src, (size_t)i, fin);
}

__global__ __launch_bounds__(256) void zero_f32(float* __restrict__ p, int n) {
    int i = blockIdx.x * 256 + threadIdx.x;
    if (i < n) p[i] = 0.f;
}

// ---------------- diagonal permutation init ---------------------------------
__global__ void diag_perm_init(int* __restrict__ perm, int* __restrict__ inv) {
    int t = blockIdx.x * blockDim.x + threadIdx.x;
    if (t >= NN) return;
    int i = t / WW, j = t % WW;
    int off = j - i;
    int start = 0;
    for (int o = -(HH - 1); o < off; ++o) {
        int lo = (0 > -o) ? 0 : -o;
        int hi = (HH - 1 < WW - 1 - o) ? (HH - 1) : (WW - 1 - o);
        start += (hi - lo + 1);
    }
    int lo0 = (0 > -off) ? 0 : -off;
    int r = start + (i - lo0);
    perm[r] = t;
    inv[t] = r;
}

// ---------------- weight transpose+pad: src (K x Nsrc) -> dst (Npad x K) ----
__global__ __launch_bounds__(256) void transpose_pad(const void* __restrict__ src,
                                                     u16* __restrict__ dst,
                                                     int K, int Nsrc,
                                                     const int* __restrict__ flags) {
    int fin = flags[0];
    __shared__ u16 tile[32][33];
    int k0 = blockIdx.x * 32, n0 = blockIdx.y * 32;
    int tx = threadIdx.x & 31, ty = threadIdx.x >> 5;
#pragma unroll
    for (int i = 0; i < 4; i++) {
        int k = k0 + ty + i * 8, n = n0 + tx;
        tile[ty + i * 8][tx] = (n < Nsrc) ? ldbf(src, (size_t)k * Nsrc + n, fin) : (u16)0;
    }
    __syncthreads();
#pragma unroll
    for (int i = 0; i < 4; i++) {
        int n = n0 + ty + i * 8, k = k0 + tx;
        dst[(size_t)n * K + k] = tile[tx][ty + i * 8];
    }
}

// ---------------- 128x128 MFMA GEMM (global_load_lds staging) ---------------
// C(MxN) = A(MxK) * Bt(NxK)^T. 256 thr = 4 waves, wave does 64x64 (4x4 MFMA).
// AM: 0 = plain rows; 1 = direction gather (dir=dbase, lda=1024)
// EM: 0 bf16; 1 split xz->xi,z (N=2048); 3 scatter-acc facc (aux0=dir_w);
//     4 final out = vf + g*acc (aux0=vf raw, aux1=g)
template <int AM, int EM>
__global__ __launch_bounds__(256) void gemm128(const u16* __restrict__ A,
                                               const u16* __restrict__ Bt,
                                               void* __restrict__ out0,
                                               void* __restrict__ out1,
                                               int M, int N, int K,
                                               const int* __restrict__ perm3,
                                               const int* __restrict__ flags,
                                               int dbase,
                                               const void* __restrict__ aux0,
                                               const float* __restrict__ aux1) {
    int fin = flags[0];
    __shared__ __align__(16) u16 As[128][32];
    __shared__ __align__(16) u16 Bs[128][32];
    int tid = threadIdx.x;
    int wave = tid >> 6, lane = tid & 63, quad = lane >> 4, l16 = lane & 15;
    int wm = wave >> 1, wn = wave & 1;
    int m0 = blockIdx.x * 128, n0 = blockIdx.y * 128;
    int r = tid >> 2, seg = (tid & 3) * 8;

    const u16 *rA0, *rA1;
    if (AM == 1) {
        int ra = m0 + r, rb = m0 + 64 + r;
        int b = (ra >> 10) & 7;
        rA0 = A + ((size_t)(b * NN + dirmap(dbase, ra & 1023, perm3))) * 1024;
        rA1 = A + ((size_t)(b * NN + dirmap(dbase, rb & 1023, perm3))) * 1024;
    } else {
        rA0 = A + (size_t)(m0 + r) * K;
        rA1 = A + (size_t)(m0 + 64 + r) * K;
    }
    const u16* rB0 = Bt + (size_t)(n0 + r) * K;
    const u16* rB1 = Bt + (size_t)(n0 + 64 + r) * K;

    v4f acc[4][4];
#pragma unroll
    for (int i = 0; i < 4; i++)
#pragma unroll
        for (int j = 0; j < 4; j++) acc[i][j] = (v4f){0.f, 0.f, 0.f, 0.f};

    for (int k0 = 0; k0 < K; k0 += 32) {
        gload_lds16(rA0 + k0 + seg, &As[r][seg]);
        gload_lds16(rA1 + k0 + seg, &As[64 + r][seg]);
        gload_lds16(rB0 + k0 + seg, &Bs[r][seg]);
        gload_lds16(rB1 + k0 + seg, &Bs[64 + r][seg]);
        __syncthreads();
        v8s af[4], bf[4];
#pragma unroll
        for (int i = 0; i < 4; i++)
            af[i] = *(const v8s*)&As[wm * 64 + i * 16 + l16][quad * 8];
#pragma unroll
        for (int j = 0; j < 4; j++)
            bf[j] = *(const v8s*)&Bs[wn * 64 + j * 16 + l16][quad * 8];
#pragma unroll
        for (int i = 0; i < 4; i++)
#pragma unroll
            for (int j = 0; j < 4; j++)
                acc[i][j] = __builtin_amdgcn_mfma_f32_16x16x32_bf16(af[i], bf[j],
                                                                    acc[i][j], 0, 0, 0);
        __syncthreads();
    }

#pragma unroll
    for (int i = 0; i < 4; i++) {
#pragma unroll
        for (int j = 0; j < 4; j++) {
#pragma unroll
            for (int rr = 0; rr < 4; rr++) {
                int row = m0 + wm * 64 + i * 16 + quad * 4 + rr;
                int col = n0 + wn * 64 + j * 16 + l16;
                float v = acc[i][j][rr];
                size_t oi = (size_t)row * N + col;
                if (EM == 0) {
                    ((u16*)out0)[oi] = f2bf(v);
                } else if (EM == 1) {
                    if (col < 1024) ((u16*)out0)[(size_t)row * 1024 + col] = f2bf(v);
                    else ((u16*)out1)[(size_t)row * 1024 + (col - 1024)] = f2bf(v);
                } else if (EM == 3) {
                    int b2 = row >> 10, t = row & 1023;
                    int q = dirmap(dbase, t, perm3);
                    float w = ldf(aux0, dbase, fin);
                    ((float*)out0)[((size_t)(b2 * NN + q)) * 1024 + col] += w * v;
                } else {
                    float g = aux1[row >> 10];
                    float res = ldf(aux0, oi, fin) + g * v;
                    if (fin) ((float*)out0)[oi] = res;
                    else ((u16*)out0)[oi] = f2bf(res);
                }
            }
        }
    }
}

// ---------------- dtbc GEMM: K-split + atomic accumulate (N=64) -------------
// grid (M/64, 8 k-slices of 128); dtbc must be zeroed first.
__global__ __launch_bounds__(256) void gemm_dtbc_ks(const u16* __restrict__ A,
                                                    const u16* __restrict__ Bt,
                                                    float* __restrict__ out0,
                                                    int M, int N, int K) {
    __shared__ u16 As[64][32];
    __shared__ u16 Bs[64][32];
    int tid = threadIdx.x;
    int wave = tid >> 6, lane = tid & 63, quad = lane >> 4, l16 = lane & 15;
    int m0 = blockIdx.x * 64;
    int kbase = blockIdx.y * 128;
    int lr = tid >> 2, seg = (tid & 3) * 8;
    const u16* arow = A + (size_t)(m0 + lr) * K + kbase;
    const u16* brow = Bt + (size_t)lr * K + kbase;
    v4f acc[4];
#pragma unroll
    for (int j = 0; j < 4; j++) acc[j] = (v4f){0.f, 0.f, 0.f, 0.f};
    for (int k0 = 0; k0 < 128; k0 += 32) {
        uint4 av = *(const uint4*)(arow + k0 + seg);
        uint4 bv = *(const uint4*)(brow + k0 + seg);
        *(uint4*)&As[lr][seg] = av;
        *(uint4*)&Bs[lr][seg] = bv;
        __syncthreads();
        v8s af = *(const v8s*)&As[wave * 16 + l16][quad * 8];
#pragma unroll
        for (int j = 0; j < 4; j++) {
            v8s bf = *(const v8s*)&Bs[j * 16 + l16][quad * 8];
            acc[j] = __builtin_amdgcn_mfma_f32_16x16x32_bf16(af, bf, acc[j], 0, 0, 0);
        }
        __syncthreads();
    }
#pragma unroll
    for (int j = 0; j < 4; j++)
#pragma unroll
        for (int rr = 0; rr < 4; rr++) {
            int row = m0 + wave * 16 + quad * 4 + rr;
            int col = j * 16 + l16;
            atomicAdd(&out0[(size_t)row * N + col], acc[j][rr]);
        }
}

// ---------------- depthwise causal conv (k=4) + SiLU ------------------------
__global__ __launch_bounds__(256) void conv_silu(const u16* __restrict__ xi,
                                                 const void* __restrict__ cw,
                                                 u16* __restrict__ xc,
                                                 const int* __restrict__ flags) {
    int fin = flags[0];
    int idx = blockIdx.x * 256 + threadIdx.x;
    int e = idx & 1023;
    int row = idx >> 10;
    int t = row & 1023;
    float acc = 0.f;
#pragma unroll
    for (int k = 0; k < 4; k++) {
        int tt = t - 3 + k;
        if (tt >= 0) acc += ldf(cw, (size_t)e * 4 + k, fin) *
                            bf2f(xi[(size_t)(row - 3 + k) * 1024 + e]);
    }
    xc[idx] = f2bf(acc * sigmoidf_(acc));
}

// ---------------- chunked parallel scan -------------------------------------
// grid per direction: (ec 4) x (chunk 32) x (b 8) = 1024 blocks x 256 threads.
template <int PASS>
__global__ __launch_bounds__(256) void scan_chunk(const float* __restrict__ dtbc,
                                                  u16* __restrict__ xcyz,
                                                  const u16* __restrict__ zb,
                                                  const void* __restrict__ A_log,
                                                  const void* __restrict__ W_dt,
                                                  const void* __restrict__ b_dt,
                                                  const int* __restrict__ flags,
                                                  float* __restrict__ hend,
                                                  float* __restrict__ dtsum) {
    int fin = flags[0];
    int bid = blockIdx.x;
    int ec = bid & 3, c = (bid >> 2) & 31, b = bid >> 7;
    int e = ec * 256 + threadIdx.x;
    __shared__ float sdt[CLEN][32];
    {
        const float* src = dtbc + ((size_t)b * 1024 + c * CLEN) * 64;
        int t = threadIdx.x >> 3, f = threadIdx.x & 7;   // 256 thr = 32 rows x 8 f4
        *(float4*)&sdt[t][f * 4] = *(const float4*)(src + (size_t)t * 64 + f * 4);
    }
    float Ae[16], wdt[16];
#pragma unroll
    for (int s = 0; s < 16; s++) Ae[s] = -__expf(ldf(A_log, (size_t)e * 16 + s, fin));
#pragma unroll
    for (int s = 0; s < 16; s++) wdt[s] = ldf(W_dt, (size_t)s * 1024 + e, fin);
    float bd = ldf(b_dt, e, fin);
    float h[16];
    if (PASS == 1) {
#pragma unroll
        for (int s = 0; s < 16; s++) h[s] = 0.f;
    } else {
#pragma unroll
        for (int s = 0; s < 16; s++)
            h[s] = hend[(((size_t)(b * NCHUNK + c)) * 16 + s) * 1024 + e];
    }
    __syncthreads();
    float ds = 0.f;
    size_t ix = ((size_t)b * 1024 + c * CLEN) * 1024 + e;
    float xv = bf2f(xcyz[ix]);                       // prefetch t=0
    float zv = (PASS == 3) ? bf2f(zb[ix]) : 0.f;
    for (int t = 0; t < CLEN; t++) {
        float xn = 0.f, zn = 0.f;
        if (t + 1 < CLEN) {                          // prefetch t+1 (overlaps compute)
            xn = bf2f(xcyz[ix + 1024]);
            if (PASS == 3) zn = bf2f(zb[ix + 1024]);
        }
        float4 d0 = *(const float4*)&sdt[t][0];
        float4 d1 = *(const float4*)&sdt[t][4];
        float4 d2 = *(const float4*)&sdt[t][8];
        float4 d3 = *(const float4*)&sdt[t][12];
        float xp = bd;
        xp += d0.x * wdt[0] + d0.y * wdt[1] + d0.z * wdt[2] + d0.w * wdt[3];
        xp += d1.x * wdt[4] + d1.y * wdt[5] + d1.z * wdt[6] + d1.w * wdt[7];
        xp += d2.x * wdt[8] + d2.y * wdt[9] + d2.z * wdt[10] + d2.w * wdt[11];
        xp += d3.x * wdt[12] + d3.y * wdt[13] + d3.z * wdt[14] + d3.w * wdt[15];
        // fast softplus: log1p(exp(x)) via HW exp/log (err ~1e-7, fine at bf16 out)
        float ex = __expf(xp);
        float dtv = (xp > 15.f) ? xp : __logf(1.f + ex);
        float4 b0 = *(const float4*)&sdt[t][16];
        float4 b1 = *(const float4*)&sdt[t][20];
        float4 b2 = *(const float4*)&sdt[t][24];
        float4 b3 = *(const float4*)&sdt[t][28];
        float bc[16] = {b0.x, b0.y, b0.z, b0.w, b1.x, b1.y, b1.z, b1.w,
                        b2.x, b2.y, b2.z, b2.w, b3.x, b3.y, b3.z, b3.w};
        float acc = 0.f;
#pragma unroll
        for (int s = 0; s < 16; s++) {
            h[s] = h[s] * __expf(Ae[s] * dtv) + bc[s] * xv;
            acc += h[s];
        }
        if (PASS == 1) ds += dtv;
        if (PASS == 3) {
            xcyz[ix] = f2bf(acc * (zv * sigmoidf_(zv)));
        }
        ix += 1024;
        xv = xn;
        zv = zn;
    }
    if (PASS == 1) {
#pragma unroll
        for (int s = 0; s < 16; s++)
            hend[(((size_t)(b * NCHUNK + c)) * 16 + s) * 1024 + e] = h[s];
        dtsum[((size_t)(b * NCHUNK + c)) * 1024 + e] = ds;
    }
}

__global__ __launch_bounds__(256) void scan_combine(float* __restrict__ hend,
                                                    const float* __restrict__ dtsum,
                                                    const void* __restrict__ A_log,
                                                    const int* __restrict__ flags) {
    int fin = flags[0];
    int b = blockIdx.x >> 2;
    int e = (blockIdx.x & 3) * 256 + threadIdx.x;
    float Ae[16];
#pragma unroll
    for (int s = 0; s < 16; s++) Ae[s] = -__expf(ldf(A_log, (size_t)e * 16 + s, fin));
    float H[16];
#pragma unroll
    for (int s = 0; s < 16; s++) H[s] = 0.f;
    for (int c = 0; c < NCHUNK; c++) {
        float ds = dtsum[((size_t)(b * NCHUNK + c)) * 1024 + e];
#pragma unroll
        for (int s = 0; s < 16; s++) {
            size_t idx = (((size_t)(b * NCHUNK + c)) * 16 + s) * 1024 + e;
            float loc = hend[idx];
            float nh = loc + __expf(Ae[s] * ds) * H[s];
            hend[idx] = H[s];
            H[s] = nh;
        }
    }
}

// ---------------- LayerNorm over fused fp32 accumulator ---------------------
__global__ __launch_bounds__(256) void ln_kernel(const float* __restrict__ facc,
                                                 const void* __restrict__ ln_g,
                                                 const void* __restrict__ ln_b,
                                                 const int* __restrict__ flags,
                                                 u16* __restrict__ fn) {
    int fin = flags[0];
    size_t base = (size_t)blockIdx.x * 1024;
    float v[4];
    float sum = 0.f, sq = 0.f;
#pragma unroll
    for (int k = 0; k < 4; k++) {
        int e = threadIdx.x + k * 256;
        float f = facc[base + e];
        v[k] = f;
        sum += f;
        sq += f * f;
    }
    __shared__ float r1[256], r2[256];
    r1[threadIdx.x] = sum;
    r2[threadIdx.x] = sq;
    __syncthreads();
    for (int s = 128; s > 0; s >>= 1) {
        if (threadIdx.x < s) {
            r1[threadIdx.x] += r1[threadIdx.x + s];
            r2[threadIdx.x] += r2[threadIdx.x + s];
        }
        __syncthreads();
    }
    float mu = r1[0] * (1.f / 1024.f);
    float var = r2[0] * (1.f / 1024.f) - mu * mu;
    float rs = rsqrtf(var + 1e-5f);
#pragma unroll
    for (int k = 0; k < 4; k++) {
        int e = threadIdx.x + k * 256;
        fn[base + e] = f2bf((v[k] - mu) * rs * ldf(ln_g, e, fin) + ldf(ln_b, e, fin));
    }
}

// ---------------- gate: partial col sums -> shared matvec -> finisher -------
__global__ __launch_bounds__(256) void gate_partial(const u16* __restrict__ vfb,
                                                    float* __restrict__ meanv) {
    int b = blockIdx.x >> 4, tc = blockIdx.x & 15;
    float s[4] = {0.f, 0.f, 0.f, 0.f};
    const u16* base = vfb + ((size_t)b * 1024 + tc * 64) * 1024;
    for (int t = 0; t < 64; t++) {
#pragma unroll
        for (int k = 0; k < 4; k++)
            s[k] += bf2f(base[(size_t)t * 1024 + threadIdx.x + k * 256]);
    }
#pragma unroll
    for (int k = 0; k < 4; k++)
        atomicAdd(&meanv[b * 1024 + threadIdx.x + k * 256], s[k]);
}

__global__ __launch_bounds__(256) void gate_mv(const float* __restrict__ meanv,
                                               const void* __restrict__ Wg1,
                                               const int* __restrict__ flags,
                                               float* __restrict__ gpart) {
    int fin = flags[0];
    int kc = blockIdx.x, j = threadIdx.x;
    __shared__ float mv[8][32];
    if (threadIdx.x < 8 * 32) {
        int b = threadIdx.x >> 5, kk = threadIdx.x & 31;
        mv[b][kk] = meanv[b * 1024 + kc * 32 + kk] * (1.f / 1024.f);
    }
    __syncthreads();
    float acc[8];
#pragma unroll
    for (int b = 0; b < 8; b++) acc[b] = 0.f;
    for (int kk = 0; kk < 32; kk++) {
        float w = ldf(Wg1, (size_t)(kc * 32 + kk) * 256 + j, fin);
#pragma unroll
        for (int b = 0; b < 8; b++) acc[b] += mv[b][kk] * w;
    }
#pragma unroll
    for (int b = 0; b < 8; b++) atomicAdd(&gpart[b * 256 + j], acc[b]);
}

__global__ __launch_bounds__(256) void gate_fin2(const float* __restrict__ gpart,
                                                 const void* __restrict__ Wg2,
                                                 const int* __restrict__ flags,
                                                 float* __restrict__ g) {
    int fin = flags[0];
    int b = blockIdx.x, j = threadIdx.x;
    __shared__ float red[256];
    float a = gpart[b * 256 + j];
    float si = a * sigmoidf_(a);
    red[j] = si * ldf(Wg2, j, fin);
    __syncthreads();
    for (int st = 128; st > 0; st >>= 1) {
        if (j < st) red[j] += red[j + st];
        __syncthreads();
    }
    if (j == 0) g[b] = sigmoidf_(red[0]);
}

// ---------------- launch ----------------------------------------------------
extern "C" void kernel_launch(void* const* d_in, const int* in_sizes, int n_in,
                              void* d_out, int out_size, void* d_ws, size_t ws_size,
                              hipStream_t stream) {
    const void* vf_raw  = d_in[0];
    const void* W_input = d_in[1];
    const void* W_in    = d_in[2];
    const void* conv_w  = d_in[3];
    const void* W_xproj = d_in[4];
    const void* W_dt    = d_in[5];
    const void* b_dt    = d_in[6];
    const void* A_log   = d_in[7];
    const void* W_outm  = d_in[8];
    const void* dir_w   = d_in[9];
    const void* ln_g    = d_in[10];
    const void* ln_b    = d_in[11];
    const void* W_outpj = d_in[12];
    const void* Wg1     = d_in[13];
    const void* Wg2     = d_in[14];

    char* ws = (char*)d_ws;
    size_t off = 0;
    auto alloc = [&](size_t bytes) -> void* {
        void* p = ws + off;
        off = (off + bytes + 255) & ~(size_t)255;
        return p;
    };
    int*   flags = (int*)alloc(256);
    int*   perm3 = (int*)alloc(NN * 4);
    int*   inv3  = (int*)alloc(NN * 4);
    float* meanv = (float*)alloc(8 * 1024 * 4);
    float* gpart = (float*)alloc(8 * 256 * 4);
    float* gbuf  = (float*)alloc(64);
    float* dtsum = (float*)alloc((size_t)8 * NCHUNK * 1024 * 4);  // 1 MB
    u16*   WtI   = (u16*)alloc((size_t)1024 * 1024 * 2);
    u16*   WtIn  = (u16*)alloc((size_t)2048 * 1024 * 2);
    u16*   WtXp  = (u16*)alloc((size_t)64 * 1024 * 2);
    u16*   WtOm  = (u16*)alloc((size_t)1024 * 1024 * 2);
    u16*   WtOp  = (u16*)alloc((size_t)1024 * 1024 * 2);
    u16*   vfb   = (u16*)alloc((size_t)M1 * 1024 * 2);   // scan hend scratch later
    u16*   xbuf  = (u16*)alloc((size_t)M1 * 1024 * 2);
    float* facc  = (float*)alloc((size_t)M1 * 1024 * 4);
    u16*   xi    = (u16*)alloc((size_t)M1 * 1024 * 2);   // later: fn
    u16*   zb    = (u16*)alloc((size_t)M1 * 1024 * 2);
    u16*   xc    = (u16*)alloc((size_t)M1 * 1024 * 2);   // becomes yz in-place
    float* dtbc  = (float*)alloc((size_t)M1 * 64 * 4);
    // peak ~125.5 MB (round-2/3/4 envelope +1 MB)
    float* hend  = (float*)vfb;  // 8*32*16*1024*4 = 16.78 MB == vfb size exactly

    detect_dtype<<<1, 64, 0, stream>>>((const u16*)vf_raw, flags);
    convert_bf<<<(M1 * 1024) / 256, 256, 0, stream>>>(vf_raw, vfb, flags, M1 * 1024);
    diag_perm_init<<<4, 256, 0, stream>>>(perm3, inv3);
    transpose_pad<<<dim3(32, 32), 256, 0, stream>>>(W_input, WtI, 1024, 1024, flags);
    transpose_pad<<<dim3(32, 64), 256, 0, stream>>>(W_in, WtIn, 1024, 2048, flags);
    transpose_pad<<<dim3(32, 2), 256, 0, stream>>>(W_xproj, WtXp, 1024, 32, flags);
    transpose_pad<<<dim3(32, 32), 256, 0, stream>>>(W_outm, WtOm, 1024, 1024, flags);
    transpose_pad<<<dim3(32, 32), 256, 0, stream>>>(W_outpj, WtOp, 1024, 1024, flags);
    zero_f32<<<(M1 * 1024) / 256, 256, 0, stream>>>(facc, M1 * 1024);
    zero_f32<<<32, 256, 0, stream>>>(meanv, 8 * 1024);
    zero_f32<<<8, 256, 0, stream>>>(gpart, 8 * 256);

    // gate (uses vfb before scan scratch aliases it — stream-ordered)
    gate_partial<<<128, 256, 0, stream>>>(vfb, meanv);
    gate_mv<<<32, 256, 0, stream>>>(meanv, Wg1, flags, gpart);
    gate_fin2<<<8, 256, 0, stream>>>(gpart, Wg2, flags, gbuf);

    // x = vf @ W_input
    gemm128<0, 0><<<dim3(64, 8), 256, 0, stream>>>(
        vfb, WtI, xbuf, nullptr, M1, 1024, 1024, perm3, flags, 0, nullptr, nullptr);

    for (int d = 0; d < 4; d++) {
        gemm128<1, 1><<<dim3(64, 16), 256, 0, stream>>>(
            xbuf, WtIn, xi, zb, M1, 2048, 1024, perm3, flags, d, nullptr, nullptr);
        conv_silu<<<M1 * 4, 256, 0, stream>>>(xi, conv_w, xc, flags);
        zero_f32<<<(M1 * 64) / 256, 256, 0, stream>>>(dtbc, M1 * 64);
        gemm_dtbc_ks<<<dim3(128, 8), 256, 0, stream>>>(xc, WtXp, dtbc, M1, 64, 1024);
        scan_chunk<1><<<1024, 256, 0, stream>>>(dtbc, xc, zb, A_log, W_dt, b_dt,
                                                flags, hend, dtsum);
        scan_combine<<<32, 256, 0, stream>>>(hend, dtsum, A_log, flags);
        scan_chunk<3><<<1024, 256, 0, stream>>>(dtbc, xc, zb, A_log, W_dt, b_dt,
                                                flags, hend, dtsum);
        gemm128<0, 3><<<dim3(64, 8), 256, 0, stream>>>(
            xc, WtOm, facc, nullptr, M1, 1024, 1024, perm3, flags, d, dir_w, nullptr);
    }

    u16* fn = xi;
    ln_kernel<<<M1, 256, 0, stream>>>(facc, ln_g, ln_b, flags, fn);
    gemm128<0, 4><<<dim3(64, 8), 256, 0, stream>>>(
        fn, WtOp, d_out, nullptr, M1, 1024, 1024, perm3, flags, 0, vf_raw, gbuf);
}

// Round 6
// 1406.065 us; speedup vs baseline: 3.5671x; 1.0002x over previous
//
#include <hip/hip_runtime.h>

typedef unsigned short u16;
typedef unsigned int u32;
typedef short v8s __attribute__((ext_vector_type(8)));
typedef float v4f __attribute__((ext_vector_type(4)));

#define B_SZ 8
#define HH 32
#define WW 32
#define NN 1024          // H*W
#define M1 (B_SZ * NN)   // 8192 rows (one direction)
#define NCHUNK 64
#define CLEN 16          // NCHUNK*CLEN = 1024

__device__ __forceinline__ float bf2f(u16 u) {
    u32 x = ((u32)u) << 16;
    return __builtin_bit_cast(float, x);
}
__device__ __forceinline__ u16 f2bf(float f) {
    u32 x = __builtin_bit_cast(u32, f);
    x = x + 0x7fffu + ((x >> 16) & 1u);
    return (u16)(x >> 16);
}
__device__ __forceinline__ float sigmoidf_(float x) { return 1.f / (1.f + __expf(-x)); }
__device__ __forceinline__ float ldf(const void* p, size_t i, int fin) {
    return fin ? ((const float*)p)[i] : bf2f(((const u16*)p)[i]);
}
__device__ __forceinline__ u16 ldbf(const void* p, size_t i, int fin) {
    return fin ? f2bf(((const float*)p)[i]) : ((const u16*)p)[i];
}
// async global->LDS, 16B per lane; LDS dest = wave-uniform base + lane*16
__device__ __forceinline__ void gload_lds16(const u16* g, u16* l) {
    __builtin_amdgcn_global_load_lds(
        (const __attribute__((address_space(1))) unsigned int*)g,
        (__attribute__((address_space(3))) unsigned int*)l, 16, 0, 0);
}
__device__ __forceinline__ int dirmap(int d, int t, const int* __restrict__ perm3) {
    if (d == 0) return t;
    if (d == 1) return (NN - 1) - t;
    if (d == 2) return (t & (HH - 1)) * WW + (t >> 5);
    return perm3[t];
}

// ---------------- input dtype sniffer ---------------------------------------
__global__ void detect_dtype(const u16* __restrict__ raw, int* __restrict__ flags) {
    if (threadIdx.x == 0 && blockIdx.x == 0) {
        int ok = 0;
        for (int i = 0; i < 512; i++) {
            int e = (raw[i] >> 7) & 0xFF;
            ok += (e >= 100 && e <= 140) ? 1 : 0;
        }
        flags[0] = (ok < 460) ? 1 : 0;
    }
}

__global__ __launch_bounds__(256) void convert_bf(const void* __restrict__ src,
                                                  u16* __restrict__ dst,
                                                  const int* __restrict__ flags, int n) {
    int fin = flags[0];
    int i = blockIdx.x * 256 + threadIdx.x;
    if (i < n) dst[i] = ldbf(src, (size_t)i, fin);
}

__global__ __launch_bounds__(256) void zero_f32(float* __restrict__ p, int n) {
    int i = blockIdx.x * 256 + threadIdx.x;
    if (i < n) p[i] = 0.f;
}

// ---------------- diagonal permutation init ---------------------------------
__global__ void diag_perm_init(int* __restrict__ perm, int* __restrict__ inv) {
    int t = blockIdx.x * blockDim.x + threadIdx.x;
    if (t >= NN) return;
    int i = t / WW, j = t % WW;
    int off = j - i;
    int start = 0;
    for (int o = -(HH - 1); o < off; ++o) {
        int lo = (0 > -o) ? 0 : -o;
        int hi = (HH - 1 < WW - 1 - o) ? (HH - 1) : (WW - 1 - o);
        start += (hi - lo + 1);
    }
    int lo0 = (0 > -off) ? 0 : -off;
    int r = start + (i - lo0);
    perm[r] = t;
    inv[t] = r;
}

// ---------------- weight transpose+pad: src (K x Nsrc) -> dst (Npad x K) ----
__global__ __launch_bounds__(256) void transpose_pad(const void* __restrict__ src,
                                                     u16* __restrict__ dst,
                                                     int K, int Nsrc,
                                                     const int* __restrict__ flags) {
    int fin = flags[0];
    __shared__ u16 tile[32][33];
    int k0 = blockIdx.x * 32, n0 = blockIdx.y * 32;
    int tx = threadIdx.x & 31, ty = threadIdx.x >> 5;
#pragma unroll
    for (int i = 0; i < 4; i++) {
        int k = k0 + ty + i * 8, n = n0 + tx;
        tile[ty + i * 8][tx] = (n < Nsrc) ? ldbf(src, (size_t)k * Nsrc + n, fin) : (u16)0;
    }
    __syncthreads();
#pragma unroll
    for (int i = 0; i < 4; i++) {
        int n = n0 + ty + i * 8, k = k0 + tx;
        dst[(size_t)n * K + k] = tile[tx][ty + i * 8];
    }
}

// ---------------- 128x128 MFMA GEMM (global_load_lds + XOR swizzle) ---------
// C(MxN) = A(MxK) * Bt(NxK)^T. 256 thr = 4 waves, wave does 64x64 (4x4 MFMA).
// LDS swizzle: phys slot p of row r holds logical 16B segment p^((r>>1)&3).
// EM: 0 bf16; 1 split xz->xi,z (N=2048); 3 scatter-acc facc (aux0=dir_w, dir=dbase);
//     4 final out = vf + g*acc (aux0=vf raw, aux1=g)
template <int EM>
__global__ __launch_bounds__(256) void gemm128(const u16* __restrict__ A,
                                               const u16* __restrict__ Bt,
                                               void* __restrict__ out0,
                                               void* __restrict__ out1,
                                               int M, int N, int K,
                                               const int* __restrict__ perm3,
                                               const int* __restrict__ flags,
                                               int dbase,
                                               const void* __restrict__ aux0,
                                               const float* __restrict__ aux1) {
    int fin = flags[0];
    __shared__ __align__(16) u16 As[128][32];
    __shared__ __align__(16) u16 Bs[128][32];
    int tid = threadIdx.x;
    int wave = tid >> 6, lane = tid & 63, quad = lane >> 4, l16 = lane & 15;
    int wm = wave >> 1, wn = wave & 1;
    int m0 = blockIdx.x * 128, n0 = blockIdx.y * 128;
    int r = tid >> 2, p = tid & 3;
    int sA = ((p ^ ((r >> 1) & 3))) * 8;   // swizzled logical segment (elems)

    const u16* rA0 = A + (size_t)(m0 + r) * K;
    const u16* rA1 = A + (size_t)(m0 + 64 + r) * K;
    const u16* rB0 = Bt + (size_t)(n0 + r) * K;
    const u16* rB1 = Bt + (size_t)(n0 + 64 + r) * K;

    v4f acc[4][4];
#pragma unroll
    for (int i = 0; i < 4; i++)
#pragma unroll
        for (int j = 0; j < 4; j++) acc[i][j] = (v4f){0.f, 0.f, 0.f, 0.f};

    int swf = ((l16 >> 1) & 3);
    for (int k0 = 0; k0 < K; k0 += 32) {
        gload_lds16(rA0 + k0 + sA, &As[r][p * 8]);
        gload_lds16(rA1 + k0 + sA, &As[64 + r][p * 8]);
        gload_lds16(rB0 + k0 + sA, &Bs[r][p * 8]);
        gload_lds16(rB1 + k0 + sA, &Bs[64 + r][p * 8]);
        __syncthreads();
        v8s af[4], bf[4];
#pragma unroll
        for (int i = 0; i < 4; i++)
            af[i] = *(const v8s*)&As[wm * 64 + i * 16 + l16][(quad ^ swf) * 8];
#pragma unroll
        for (int j = 0; j < 4; j++)
            bf[j] = *(const v8s*)&Bs[wn * 64 + j * 16 + l16][(quad ^ swf) * 8];
#pragma unroll
        for (int i = 0; i < 4; i++)
#pragma unroll
            for (int j = 0; j < 4; j++)
                acc[i][j] = __builtin_amdgcn_mfma_f32_16x16x32_bf16(af[i], bf[j],
                                                                    acc[i][j], 0, 0, 0);
        __syncthreads();
    }

#pragma unroll
    for (int i = 0; i < 4; i++) {
#pragma unroll
        for (int j = 0; j < 4; j++) {
#pragma unroll
            for (int rr = 0; rr < 4; rr++) {
                int row = m0 + wm * 64 + i * 16 + quad * 4 + rr;
                int col = n0 + wn * 64 + j * 16 + l16;
                float v = acc[i][j][rr];
                size_t oi = (size_t)row * N + col;
                if (EM == 0) {
                    ((u16*)out0)[oi] = f2bf(v);
                } else if (EM == 1) {
                    if (col < 1024) ((u16*)out0)[(size_t)row * 1024 + col] = f2bf(v);
                    else ((u16*)out1)[(size_t)row * 1024 + (col - 1024)] = f2bf(v);
                } else if (EM == 3) {
                    int b2 = row >> 10, t = row & 1023;
                    int q = dirmap(dbase, t, perm3);
                    float w = ldf(aux0, dbase, fin);
                    ((float*)out0)[((size_t)(b2 * NN + q)) * 1024 + col] += w * v;
                } else {
                    float g = aux1[row >> 10];
                    float res = ldf(aux0, oi, fin) + g * v;
                    if (fin) ((float*)out0)[oi] = res;
                    else ((u16*)out0)[oi] = f2bf(res);
                }
            }
        }
    }
}

// ---------------- dtbc GEMM: K-split + atomic accumulate (N=64) -------------
// grid (M/64, 8 k-slices of 128); dtbc must be zeroed first.
__global__ __launch_bounds__(256) void gemm_dtbc_ks(const u16* __restrict__ A,
                                                    const u16* __restrict__ Bt,
                                                    float* __restrict__ out0,
                                                    int M, int N, int K) {
    __shared__ u16 As[64][32];
    __shared__ u16 Bs[64][32];
    int tid = threadIdx.x;
    int wave = tid >> 6, lane = tid & 63, quad = lane >> 4, l16 = lane & 15;
    int m0 = blockIdx.x * 64;
    int kbase = blockIdx.y * 128;
    int lr = tid >> 2, p = tid & 3;
    int sA = ((p ^ ((lr >> 1) & 3))) * 8;
    const u16* arow = A + (size_t)(m0 + lr) * K + kbase;
    const u16* brow = Bt + (size_t)lr * K + kbase;
    v4f acc[4];
#pragma unroll
    for (int j = 0; j < 4; j++) acc[j] = (v4f){0.f, 0.f, 0.f, 0.f};
    int swf = ((l16 >> 1) & 3);
    for (int k0 = 0; k0 < 128; k0 += 32) {
        uint4 av = *(const uint4*)(arow + k0 + sA);
        uint4 bv = *(const uint4*)(brow + k0 + sA);
        *(uint4*)&As[lr][p * 8] = av;
        *(uint4*)&Bs[lr][p * 8] = bv;
        __syncthreads();
        v8s af = *(const v8s*)&As[wave * 16 + l16][(quad ^ swf) * 8];
#pragma unroll
        for (int j = 0; j < 4; j++) {
            v8s bf = *(const v8s*)&Bs[j * 16 + l16][(quad ^ swf) * 8];
            acc[j] = __builtin_amdgcn_mfma_f32_16x16x32_bf16(af, bf, acc[j], 0, 0, 0);
        }
        __syncthreads();
    }
#pragma unroll
    for (int j = 0; j < 4; j++)
#pragma unroll
        for (int rr = 0; rr < 4; rr++) {
            int row = m0 + wave * 16 + quad * 4 + rr;
            int col = j * 16 + l16;
            atomicAdd(&out0[(size_t)row * N + col], acc[j][rr]);
        }
}

// ---------------- depthwise causal conv + SiLU, gather folded in ------------
// block = one (b,t) row; thread handles 4 consecutive e. xi in natural order,
// xc written in direction order: xc[b,t] = silu(conv(xi[b,P_d(t-3+k)])).
__global__ __launch_bounds__(256) void conv_silu_d(const u16* __restrict__ xi,
                                                   const void* __restrict__ cw,
                                                   u16* __restrict__ xc,
                                                   const int* __restrict__ flags,
                                                   int d, const int* __restrict__ perm3) {
    int fin = flags[0];
    int row = blockIdx.x;            // b*1024 + t (direction order)
    int t = row & 1023, b = row >> 10;
    int e0 = threadIdx.x * 4;
    float a0 = 0.f, a1 = 0.f, a2 = 0.f, a3 = 0.f;
#pragma unroll
    for (int k = 0; k < 4; k++) {
        int tt = t - 3 + k;
        if (tt >= 0) {
            int src = b * 1024 + dirmap(d, tt, perm3);
            uint2 v = *(const uint2*)(xi + (size_t)src * 1024 + e0);
            const u16* vs = (const u16*)&v;
            a0 += ldf(cw, (size_t)(e0 + 0) * 4 + k, fin) * bf2f(vs[0]);
            a1 += ldf(cw, (size_t)(e0 + 1) * 4 + k, fin) * bf2f(vs[1]);
            a2 += ldf(cw, (size_t)(e0 + 2) * 4 + k, fin) * bf2f(vs[2]);
            a3 += ldf(cw, (size_t)(e0 + 3) * 4 + k, fin) * bf2f(vs[3]);
        }
    }
    u16 o[4];
    o[0] = f2bf(a0 * sigmoidf_(a0));
    o[1] = f2bf(a1 * sigmoidf_(a1));
    o[2] = f2bf(a2 * sigmoidf_(a2));
    o[3] = f2bf(a3 * sigmoidf_(a3));
    *(uint2*)(xc + (size_t)row * 1024 + e0) = *(const uint2*)o;
}

// ---------------- chunked parallel scan -------------------------------------
// grid per direction: (ec 4) x (chunk 64) x (b 8) = 2048 blocks x 256 threads.
// PASS3 reads z gathered through P_d (z kept in natural order).
template <int PASS>
__global__ __launch_bounds__(256) void scan_chunk(const float* __restrict__ dtbc,
                                                  u16* __restrict__ xcyz,
                                                  const u16* __restrict__ zb,
                                                  const void* __restrict__ A_log,
                                                  const void* __restrict__ W_dt,
                                                  const void* __restrict__ b_dt,
                                                  const int* __restrict__ flags,
                                                  float* __restrict__ hend,
                                                  float* __restrict__ dtsum,
                                                  int dbase,
                                                  const int* __restrict__ perm3) {
    int fin = flags[0];
    int bid = blockIdx.x;
    int ec = bid & 3, c = (bid >> 2) & 63, b = bid >> 8;
    int e = ec * 256 + threadIdx.x;
    __shared__ float sdt[CLEN][32];
    __shared__ int s_perm[CLEN];
    {
        const float* src = dtbc + ((size_t)b * 1024 + c * CLEN) * 64;
        if (threadIdx.x < 128) {
            int t = threadIdx.x >> 3, f = threadIdx.x & 7;
            *(float4*)&sdt[t][f * 4] = *(const float4*)(src + (size_t)t * 64 + f * 4);
        }
        if (PASS == 3 && threadIdx.x < CLEN)
            s_perm[threadIdx.x] = dirmap(dbase, c * CLEN + (int)threadIdx.x, perm3);
    }
    float Ae[16], wdt[16];
#pragma unroll
    for (int s = 0; s < 16; s++) Ae[s] = -__expf(ldf(A_log, (size_t)e * 16 + s, fin));
#pragma unroll
    for (int s = 0; s < 16; s++) wdt[s] = ldf(W_dt, (size_t)s * 1024 + e, fin);
    float bd = ldf(b_dt, e, fin);
    float h[16];
    if (PASS == 1) {
#pragma unroll
        for (int s = 0; s < 16; s++) h[s] = 0.f;
    } else {
#pragma unroll
        for (int s = 0; s < 16; s++)
            h[s] = hend[(((size_t)(b * NCHUNK + c)) * 16 + s) * 1024 + e];
    }
    __syncthreads();
    float ds = 0.f;
    size_t ix = ((size_t)b * 1024 + c * CLEN) * 1024 + e;
    size_t zbase = (size_t)b * 1024 * 1024 + e;
    float xv = bf2f(xcyz[ix]);                       // prefetch t=0
    float zv = (PASS == 3) ? bf2f(zb[zbase + (size_t)s_perm[0] * 1024]) : 0.f;
    for (int t = 0; t < CLEN; t++) {
        float xn = 0.f, zn = 0.f;
        if (t + 1 < CLEN) {                          // prefetch t+1
            xn = bf2f(xcyz[ix + 1024]);
            if (PASS == 3) zn = bf2f(zb[zbase + (size_t)s_perm[t + 1] * 1024]);
        }
        float4 d0 = *(const float4*)&sdt[t][0];
        float4 d1 = *(const float4*)&sdt[t][4];
        float4 d2 = *(const float4*)&sdt[t][8];
        float4 d3 = *(const float4*)&sdt[t][12];
        float xp = bd;
        xp += d0.x * wdt[0] + d0.y * wdt[1] + d0.z * wdt[2] + d0.w * wdt[3];
        xp += d1.x * wdt[4] + d1.y * wdt[5] + d1.z * wdt[6] + d1.w * wdt[7];
        xp += d2.x * wdt[8] + d2.y * wdt[9] + d2.z * wdt[10] + d2.w * wdt[11];
        xp += d3.x * wdt[12] + d3.y * wdt[13] + d3.z * wdt[14] + d3.w * wdt[15];
        float ex = __expf(xp);
        float dtv = (xp > 15.f) ? xp : __logf(1.f + ex);   // fast softplus
        float4 b0 = *(const float4*)&sdt[t][16];
        float4 b1 = *(const float4*)&sdt[t][20];
        float4 b2 = *(const float4*)&sdt[t][24];
        float4 b3 = *(const float4*)&sdt[t][28];
        float bc[16] = {b0.x, b0.y, b0.z, b0.w, b1.x, b1.y, b1.z, b1.w,
                        b2.x, b2.y, b2.z, b2.w, b3.x, b3.y, b3.z, b3.w};
        float acc = 0.f;
#pragma unroll
        for (int s = 0; s < 16; s++) {
            h[s] = h[s] * __expf(Ae[s] * dtv) + bc[s] * xv;
            acc += h[s];
        }
        if (PASS == 1) ds += dtv;
        if (PASS == 3) {
            xcyz[ix] = f2bf(acc * (zv * sigmoidf_(zv)));
        }
        ix += 1024;
        xv = xn;
        zv = zn;
    }
    if (PASS == 1) {
#pragma unroll
        for (int s = 0; s < 16; s++)
            hend[(((size_t)(b * NCHUNK + c)) * 16 + s) * 1024 + e] = h[s];
        dtsum[((size_t)(b * NCHUNK + c)) * 1024 + e] = ds;
    }
}

__global__ __launch_bounds__(256) void scan_combine(float* __restrict__ hend,
                                                    const float* __restrict__ dtsum,
                                                    const void* __restrict__ A_log,
                                                    const int* __restrict__ flags) {
    int fin = flags[0];
    int b = blockIdx.x >> 2;
    int e = (blockIdx.x & 3) * 256 + threadIdx.x;
    float Ae[16];
#pragma unroll
    for (int s = 0; s < 16; s++) Ae[s] = -__expf(ldf(A_log, (size_t)e * 16 + s, fin));
    float H[16];
#pragma unroll
    for (int s = 0; s < 16; s++) H[s] = 0.f;
    for (int c = 0; c < NCHUNK; c++) {
        float ds = dtsum[((size_t)(b * NCHUNK + c)) * 1024 + e];
#pragma unroll
        for (int s = 0; s < 16; s++) {
            size_t idx = (((size_t)(b * NCHUNK + c)) * 16 + s) * 1024 + e;
            float loc = hend[idx];
            float nh = loc + __expf(Ae[s] * ds) * H[s];
            hend[idx] = H[s];
            H[s] = nh;
        }
    }
}

// ---------------- LayerNorm over fused fp32 accumulator ---------------------
__global__ __launch_bounds__(256) void ln_kernel(const float* __restrict__ facc,
                                                 const void* __restrict__ ln_g,
                                                 const void* __restrict__ ln_b,
                                                 const int* __restrict__ flags,
                                                 u16* __restrict__ fn) {
    int fin = flags[0];
    size_t base = (size_t)blockIdx.x * 1024;
    float v[4];
    float sum = 0.f, sq = 0.f;
#pragma unroll
    for (int k = 0; k < 4; k++) {
        int e = threadIdx.x + k * 256;
        float f = facc[base + e];
        v[k] = f;
        sum += f;
        sq += f * f;
    }
    __shared__ float r1[256], r2[256];
    r1[threadIdx.x] = sum;
    r2[threadIdx.x] = sq;
    __syncthreads();
    for (int s = 128; s > 0; s >>= 1) {
        if (threadIdx.x < s) {
            r1[threadIdx.x] += r1[threadIdx.x + s];
            r2[threadIdx.x] += r2[threadIdx.x + s];
        }
        __syncthreads();
    }
    float mu = r1[0] * (1.f / 1024.f);
    float var = r2[0] * (1.f / 1024.f) - mu * mu;
    float rs = rsqrtf(var + 1e-5f);
#pragma unroll
    for (int k = 0; k < 4; k++) {
        int e = threadIdx.x + k * 256;
        fn[base + e] = f2bf((v[k] - mu) * rs * ldf(ln_g, e, fin) + ldf(ln_b, e, fin));
    }
}

// ---------------- gate: partial col sums -> shared matvec -> finisher -------
__global__ __launch_bounds__(256) void gate_partial(const u16* __restrict__ vfb,
                                                    float* __restrict__ meanv) {
    int b = blockIdx.x >> 4, tc = blockIdx.x & 15;
    float s[4] = {0.f, 0.f, 0.f, 0.f};
    const u16* base = vfb + ((size_t)b * 1024 + tc * 64) * 1024;
    for (int t = 0; t < 64; t++) {
#pragma unroll
        for (int k = 0; k < 4; k++)
            s[k] += bf2f(base[(size_t)t * 1024 + threadIdx.x + k * 256]);
    }
#pragma unroll
    for (int k = 0; k < 4; k++)
        atomicAdd(&meanv[b * 1024 + threadIdx.x + k * 256], s[k]);
}

__global__ __launch_bounds__(256) void gate_mv(const float* __restrict__ meanv,
                                               const void* __restrict__ Wg1,
                                               const int* __restrict__ flags,
                                               float* __restrict__ gpart) {
    int fin = flags[0];
    int kc = blockIdx.x, j = threadIdx.x;
    __shared__ float mv[8][32];
    if (threadIdx.x < 8 * 32) {
        int b = threadIdx.x >> 5, kk = threadIdx.x & 31;
        mv[b][kk] = meanv[b * 1024 + kc * 32 + kk] * (1.f / 1024.f);
    }
    __syncthreads();
    float acc[8];
#pragma unroll
    for (int b = 0; b < 8; b++) acc[b] = 0.f;
    for (int kk = 0; kk < 32; kk++) {
        float w = ldf(Wg1, (size_t)(kc * 32 + kk) * 256 + j, fin);
#pragma unroll
        for (int b = 0; b < 8; b++) acc[b] += mv[b][kk] * w;
    }
#pragma unroll
    for (int b = 0; b < 8; b++) atomicAdd(&gpart[b * 256 + j], acc[b]);
}

__global__ __launch_bounds__(256) void gate_fin2(const float* __restrict__ gpart,
                                                 const void* __restrict__ Wg2,
                                                 const int* __restrict__ flags,
                                                 float* __restrict__ g) {
    int fin = flags[0];
    int b = blockIdx.x, j = threadIdx.x;
    __shared__ float red[256];
    float a = gpart[b * 256 + j];
    float si = a * sigmoidf_(a);
    red[j] = si * ldf(Wg2, j, fin);
    __syncthreads();
    for (int st = 128; st > 0; st >>= 1) {
        if (j < st) red[j] += red[j + st];
        __syncthreads();
    }
    if (j == 0) g[b] = sigmoidf_(red[0]);
}

// ---------------- launch ----------------------------------------------------
extern "C" void kernel_launch(void* const* d_in, const int* in_sizes, int n_in,
                              void* d_out, int out_size, void* d_ws, size_t ws_size,
                              hipStream_t stream) {
    const void* vf_raw  = d_in[0];
    const void* W_input = d_in[1];
    const void* W_in    = d_in[2];
    const void* conv_w  = d_in[3];
    const void* W_xproj = d_in[4];
    const void* W_dt    = d_in[5];
    const void* b_dt    = d_in[6];
    const void* A_log   = d_in[7];
    const void* W_outm  = d_in[8];
    const void* dir_w   = d_in[9];
    const void* ln_g    = d_in[10];
    const void* ln_b    = d_in[11];
    const void* W_outpj = d_in[12];
    const void* Wg1     = d_in[13];
    const void* Wg2     = d_in[14];

    char* ws = (char*)d_ws;
    size_t off = 0;
    auto alloc = [&](size_t bytes) -> void* {
        void* p = ws + off;
        off = (off + bytes + 255) & ~(size_t)255;
        return p;
    };
    int*   flags = (int*)alloc(256);
    int*   perm3 = (int*)alloc(NN * 4);
    int*   inv3  = (int*)alloc(NN * 4);
    float* meanv = (float*)alloc(8 * 1024 * 4);
    float* gpart = (float*)alloc(8 * 256 * 4);
    float* gbuf  = (float*)alloc(64);
    float* dtsum = (float*)alloc((size_t)8 * NCHUNK * 1024 * 4);  // 2 MB
    u16*   WtI   = (u16*)alloc((size_t)1024 * 1024 * 2);
    u16*   WtIn  = (u16*)alloc((size_t)2048 * 1024 * 2);
    u16*   WtXp  = (u16*)alloc((size_t)64 * 1024 * 2);
    u16*   WtOm  = (u16*)alloc((size_t)1024 * 1024 * 2);
    u16*   WtOp  = (u16*)alloc((size_t)1024 * 1024 * 2);
    u16*   vfb   = (u16*)alloc((size_t)M1 * 1024 * 2);   // 16 MB; hend aliases
    u16*   xbuf  = (u16*)alloc((size_t)M1 * 1024 * 2);   // 16 MB; hend aliases
    float* facc  = (float*)alloc((size_t)M1 * 1024 * 4);
    u16*   xi    = (u16*)alloc((size_t)M1 * 1024 * 2);   // later: fn
    u16*   zb    = (u16*)alloc((size_t)M1 * 1024 * 2);
    u16*   xc    = (u16*)alloc((size_t)M1 * 1024 * 2);   // per-d; yz in-place
    float* dtbc  = (float*)alloc((size_t)M1 * 64 * 4);
    // peak ~126.5 MB (proven envelope +1 MB)
    // hend = 8*64*16*1024 f32 = 32 MB — exactly vfb(16MB)+xbuf(16MB), both dead
    // once stage-2 has run (gate uses vfb before; stage-2 reads xbuf before).
    float* hend  = (float*)vfb;

    detect_dtype<<<1, 64, 0, stream>>>((const u16*)vf_raw, flags);
    convert_bf<<<(M1 * 1024) / 256, 256, 0, stream>>>(vf_raw, vfb, flags, M1 * 1024);
    diag_perm_init<<<4, 256, 0, stream>>>(perm3, inv3);
    transpose_pad<<<dim3(32, 32), 256, 0, stream>>>(W_input, WtI, 1024, 1024, flags);
    transpose_pad<<<dim3(32, 64), 256, 0, stream>>>(W_in, WtIn, 1024, 2048, flags);
    transpose_pad<<<dim3(32, 2), 256, 0, stream>>>(W_xproj, WtXp, 1024, 32, flags);
    transpose_pad<<<dim3(32, 32), 256, 0, stream>>>(W_outm, WtOm, 1024, 1024, flags);
    transpose_pad<<<dim3(32, 32), 256, 0, stream>>>(W_outpj, WtOp, 1024, 1024, flags);
    zero_f32<<<(M1 * 1024) / 256, 256, 0, stream>>>(facc, M1 * 1024);
    zero_f32<<<32, 256, 0, stream>>>(meanv, 8 * 1024);
    zero_f32<<<8, 256, 0, stream>>>(gpart, 8 * 256);

    // gate (uses vfb before hend aliases it — stream-ordered)
    gate_partial<<<128, 256, 0, stream>>>(vfb, meanv);
    gate_mv<<<32, 256, 0, stream>>>(meanv, Wg1, flags, gpart);
    gate_fin2<<<8, 256, 0, stream>>>(gpart, Wg2, flags, gbuf);

    // stage 1: x = vf @ W_input
    gemm128<0><<<dim3(64, 8), 256, 0, stream>>>(
        vfb, WtI, xbuf, nullptr, M1, 1024, 1024, perm3, flags, 0, nullptr, nullptr);
    // stage 2 (ONCE — gather commutes with the GEMM): xz = x @ W_in -> xi, z
    gemm128<1><<<dim3(64, 16), 256, 0, stream>>>(
        xbuf, WtIn, xi, zb, M1, 2048, 1024, perm3, flags, 0, nullptr, nullptr);

    for (int d = 0; d < 4; d++) {
        conv_silu_d<<<M1, 256, 0, stream>>>(xi, conv_w, xc, flags, d, perm3);
        zero_f32<<<(M1 * 64) / 256, 256, 0, stream>>>(dtbc, M1 * 64);
        gemm_dtbc_ks<<<dim3(128, 8), 256, 0, stream>>>(xc, WtXp, dtbc, M1, 64, 1024);
        scan_chunk<1><<<2048, 256, 0, stream>>>(dtbc, xc, zb, A_log, W_dt, b_dt,
                                                flags, hend, dtsum, d, perm3);
        scan_combine<<<32, 256, 0, stream>>>(hend, dtsum, A_log, flags);
        scan_chunk<3><<<2048, 256, 0, stream>>>(dtbc, xc, zb, A_log, W_dt, b_dt,
                                                flags, hend, dtsum, d, perm3);
        gemm128<3><<<dim3(64, 8), 256, 0, stream>>>(
            xc, WtOm, facc, nullptr, M1, 1024, 1024, perm3, flags, d, dir_w, nullptr);
    }

    u16* fn = xi;  // xi dead after d=3 conv
    ln_kernel<<<M1, 256, 0, stream>>>(facc, ln_g, ln_b, flags, fn);
    gemm128<4><<<dim3(64, 8), 256, 0, stream>>>(
        fn, WtOp, d_out, nullptr, M1, 1024, 1024, perm3, flags, 0, vf_raw, gbuf);
}

// Round 7
// 1076.599 us; speedup vs baseline: 4.6587x; 1.3060x over previous
//
#include <hip/hip_runtime.h>

typedef unsigned short u16;
typedef unsigned int u32;
typedef short v8s __attribute__((ext_vector_type(8)));
typedef float v4f __attribute__((ext_vector_type(4)));

#define B_SZ 8
#define HH 32
#define WW 32
#define NN 1024          // H*W
#define M1 (B_SZ * NN)   // 8192 rows (one direction)
#define NCHUNK 32
#define CLEN 32          // NCHUNK*CLEN = 1024
#define CTB 8            // conv t-rows per block

__device__ __forceinline__ float bf2f(u16 u) {
    u32 x = ((u32)u) << 16;
    return __builtin_bit_cast(float, x);
}
__device__ __forceinline__ u16 f2bf(float f) {
    u32 x = __builtin_bit_cast(u32, f);
    x = x + 0x7fffu + ((x >> 16) & 1u);
    return (u16)(x >> 16);
}
__device__ __forceinline__ float sigmoidf_(float x) { return 1.f / (1.f + __expf(-x)); }
__device__ __forceinline__ float ldf(const void* p, size_t i, int fin) {
    return fin ? ((const float*)p)[i] : bf2f(((const u16*)p)[i]);
}
__device__ __forceinline__ u16 ldbf(const void* p, size_t i, int fin) {
    return fin ? f2bf(((const float*)p)[i]) : ((const u16*)p)[i];
}
// async global->LDS, 16B per lane; LDS dest = wave-uniform base + lane*16
__device__ __forceinline__ void gload_lds16(const u16* g, u16* l) {
    __builtin_amdgcn_global_load_lds(
        (const __attribute__((address_space(1))) unsigned int*)g,
        (__attribute__((address_space(3))) unsigned int*)l, 16, 0, 0);
}
__device__ __forceinline__ int dirmap(int d, int t, const int* __restrict__ perm3) {
    if (d == 0) return t;
    if (d == 1) return (NN - 1) - t;
    if (d == 2) return (t & (HH - 1)) * WW + (t >> 5);
    return perm3[t];
}

// ---------------- input dtype sniffer ---------------------------------------
__global__ void detect_dtype(const u16* __restrict__ raw, int* __restrict__ flags) {
    if (threadIdx.x == 0 && blockIdx.x == 0) {
        int ok = 0;
        for (int i = 0; i < 512; i++) {
            int e = (raw[i] >> 7) & 0xFF;
            ok += (e >= 100 && e <= 140) ? 1 : 0;
        }
        flags[0] = (ok < 460) ? 1 : 0;
    }
}

__global__ __launch_bounds__(256) void convert_bf(const void* __restrict__ src,
                                                  u16* __restrict__ dst,
                                                  const int* __restrict__ flags, int n) {
    int fin = flags[0];
    int i = blockIdx.x * 256 + threadIdx.x;
    if (i < n) dst[i] = ldbf(src, (size_t)i, fin);
}

__global__ __launch_bounds__(256) void zero_f32(float* __restrict__ p, int n) {
    int i = blockIdx.x * 256 + threadIdx.x;
    if (i < n) p[i] = 0.f;
}

// ---------------- diagonal permutation init ---------------------------------
__global__ void diag_perm_init(int* __restrict__ perm, int* __restrict__ inv) {
    int t = blockIdx.x * blockDim.x + threadIdx.x;
    if (t >= NN) return;
    int i = t / WW, j = t % WW;
    int off = j - i;
    int start = 0;
    for (int o = -(HH - 1); o < off; ++o) {
        int lo = (0 > -o) ? 0 : -o;
        int hi = (HH - 1 < WW - 1 - o) ? (HH - 1) : (WW - 1 - o);
        start += (hi - lo + 1);
    }
    int lo0 = (0 > -off) ? 0 : -off;
    int r = start + (i - lo0);
    perm[r] = t;
    inv[t] = r;
}

// ---------------- weight transpose+pad: src (K x Nsrc) -> dst (Npad x K) ----
__global__ __launch_bounds__(256) void transpose_pad(const void* __restrict__ src,
                                                     u16* __restrict__ dst,
                                                     int K, int Nsrc,
                                                     const int* __restrict__ flags) {
    int fin = flags[0];
    __shared__ u16 tile[32][33];
    int k0 = blockIdx.x * 32, n0 = blockIdx.y * 32;
    int tx = threadIdx.x & 31, ty = threadIdx.x >> 5;
#pragma unroll
    for (int i = 0; i < 4; i++) {
        int k = k0 + ty + i * 8, n = n0 + tx;
        tile[ty + i * 8][tx] = (n < Nsrc) ? ldbf(src, (size_t)k * Nsrc + n, fin) : (u16)0;
    }
    __syncthreads();
#pragma unroll
    for (int i = 0; i < 4; i++) {
        int n = n0 + ty + i * 8, k = k0 + tx;
        dst[(size_t)n * K + k] = tile[tx][ty + i * 8];
    }
}

// ---------------- 128x128 MFMA GEMM (global_load_lds + XOR swizzle) ---------
// C(MxN) = A(MxK) * Bt(NxK)^T. 256 thr = 4 waves, wave does 64x64 (4x4 MFMA).
// LDS swizzle: phys slot p of row r holds logical 16B segment p^((r>>1)&3).
// EM: 0 bf16; 1 split xz->xi,z (N=2048); 3 scatter-acc facc (aux0=dir_w, dir=dbase);
//     4 final out = vf + g*acc (aux0=vf raw, aux1=g)
template <int EM>
__global__ __launch_bounds__(256) void gemm128(const u16* __restrict__ A,
                                               const u16* __restrict__ Bt,
                                               void* __restrict__ out0,
                                               void* __restrict__ out1,
                                               int M, int N, int K,
                                               const int* __restrict__ perm3,
                                               const int* __restrict__ flags,
                                               int dbase,
                                               const void* __restrict__ aux0,
                                               const float* __restrict__ aux1) {
    int fin = flags[0];
    __shared__ __align__(16) u16 As[128][32];
    __shared__ __align__(16) u16 Bs[128][32];
    int tid = threadIdx.x;
    int wave = tid >> 6, lane = tid & 63, quad = lane >> 4, l16 = lane & 15;
    int wm = wave >> 1, wn = wave & 1;
    int m0 = blockIdx.x * 128, n0 = blockIdx.y * 128;
    int r = tid >> 2, p = tid & 3;
    int sA = ((p ^ ((r >> 1) & 3))) * 8;   // swizzled logical segment (elems)

    const u16* rA0 = A + (size_t)(m0 + r) * K;
    const u16* rA1 = A + (size_t)(m0 + 64 + r) * K;
    const u16* rB0 = Bt + (size_t)(n0 + r) * K;
    const u16* rB1 = Bt + (size_t)(n0 + 64 + r) * K;

    v4f acc[4][4];
#pragma unroll
    for (int i = 0; i < 4; i++)
#pragma unroll
        for (int j = 0; j < 4; j++) acc[i][j] = (v4f){0.f, 0.f, 0.f, 0.f};

    int swf = ((l16 >> 1) & 3);
    for (int k0 = 0; k0 < K; k0 += 32) {
        gload_lds16(rA0 + k0 + sA, &As[r][p * 8]);
        gload_lds16(rA1 + k0 + sA, &As[64 + r][p * 8]);
        gload_lds16(rB0 + k0 + sA, &Bs[r][p * 8]);
        gload_lds16(rB1 + k0 + sA, &Bs[64 + r][p * 8]);
        __syncthreads();
        v8s af[4], bf[4];
#pragma unroll
        for (int i = 0; i < 4; i++)
            af[i] = *(const v8s*)&As[wm * 64 + i * 16 + l16][(quad ^ swf) * 8];
#pragma unroll
        for (int j = 0; j < 4; j++)
            bf[j] = *(const v8s*)&Bs[wn * 64 + j * 16 + l16][(quad ^ swf) * 8];
#pragma unroll
        for (int i = 0; i < 4; i++)
#pragma unroll
            for (int j = 0; j < 4; j++)
                acc[i][j] = __builtin_amdgcn_mfma_f32_16x16x32_bf16(af[i], bf[j],
                                                                    acc[i][j], 0, 0, 0);
        __syncthreads();
    }

#pragma unroll
    for (int i = 0; i < 4; i++) {
#pragma unroll
        for (int j = 0; j < 4; j++) {
#pragma unroll
            for (int rr = 0; rr < 4; rr++) {
                int row = m0 + wm * 64 + i * 16 + quad * 4 + rr;
                int col = n0 + wn * 64 + j * 16 + l16;
                float v = acc[i][j][rr];
                size_t oi = (size_t)row * N + col;
                if (EM == 0) {
                    ((u16*)out0)[oi] = f2bf(v);
                } else if (EM == 1) {
                    if (col < 1024) ((u16*)out0)[(size_t)row * 1024 + col] = f2bf(v);
                    else ((u16*)out1)[(size_t)row * 1024 + (col - 1024)] = f2bf(v);
                } else if (EM == 3) {
                    int b2 = row >> 10, t = row & 1023;
                    int q = dirmap(dbase, t, perm3);
                    float w = ldf(aux0, dbase, fin);
                    ((float*)out0)[((size_t)(b2 * NN + q)) * 1024 + col] += w * v;
                } else {
                    float g = aux1[row >> 10];
                    float res = ldf(aux0, oi, fin) + g * v;
                    if (fin) ((float*)out0)[oi] = res;
                    else ((u16*)out0)[oi] = f2bf(res);
                }
            }
        }
    }
}

// ---------------- dtbc GEMM: K-split + atomic accumulate (N=64) -------------
__global__ __launch_bounds__(256) void gemm_dtbc_ks(const u16* __restrict__ A,
                                                    const u16* __restrict__ Bt,
                                                    float* __restrict__ out0,
                                                    int M, int N, int K) {
    __shared__ u16 As[64][32];
    __shared__ u16 Bs[64][32];
    int tid = threadIdx.x;
    int wave = tid >> 6, lane = tid & 63, quad = lane >> 4, l16 = lane & 15;
    int m0 = blockIdx.x * 64;
    int kbase = blockIdx.y * 128;
    int lr = tid >> 2, p = tid & 3;
    int sA = ((p ^ ((lr >> 1) & 3))) * 8;
    const u16* arow = A + (size_t)(m0 + lr) * K + kbase;
    const u16* brow = Bt + (size_t)lr * K + kbase;
    v4f acc[4];
#pragma unroll
    for (int j = 0; j < 4; j++) acc[j] = (v4f){0.f, 0.f, 0.f, 0.f};
    int swf = ((l16 >> 1) & 3);
    for (int k0 = 0; k0 < 128; k0 += 32) {
        uint4 av = *(const uint4*)(arow + k0 + sA);
        uint4 bv = *(const uint4*)(brow + k0 + sA);
        *(uint4*)&As[lr][p * 8] = av;
        *(uint4*)&Bs[lr][p * 8] = bv;
        __syncthreads();
        v8s af = *(const v8s*)&As[wave * 16 + l16][(quad ^ swf) * 8];
#pragma unroll
        for (int j = 0; j < 4; j++) {
            v8s bf = *(const v8s*)&Bs[j * 16 + l16][(quad ^ swf) * 8];
            acc[j] = __builtin_amdgcn_mfma_f32_16x16x32_bf16(af, bf, acc[j], 0, 0, 0);
        }
        __syncthreads();
    }
#pragma unroll
    for (int j = 0; j < 4; j++)
#pragma unroll
        for (int rr = 0; rr < 4; rr++) {
            int row = m0 + wave * 16 + quad * 4 + rr;
            int col = j * 16 + l16;
            atomicAdd(&out0[(size_t)row * N + col], acc[j][rr]);
        }
}

// ---------------- tiled depthwise conv + SiLU (gather folded, LDS reuse) ----
// block = (b, chunk of CTB t-rows); stages CTB+3 gathered rows into LDS once,
// computes CTB output rows. 1024 blocks x 256 threads.
__global__ __launch_bounds__(256) void conv_tile(const u16* __restrict__ xi,
                                                 const void* __restrict__ cw,
                                                 u16* __restrict__ xc,
                                                 const int* __restrict__ flags,
                                                 int d, const int* __restrict__ perm3) {
    int fin = flags[0];
    int blk = blockIdx.x;
    int b = blk >> 7, tc = blk & 127;
    int t0 = tc * CTB;
    __shared__ u16 rows[CTB + 3][1024];
    __shared__ int sp[CTB + 3];
    if (threadIdx.x < CTB + 3) {
        int tt = t0 - 3 + (int)threadIdx.x;
        sp[threadIdx.x] = (tt >= 0) ? dirmap(d, tt, perm3) : -1;
    }
    __syncthreads();
    for (int i = threadIdx.x; i < (CTB + 3) * 128; i += 256) {
        int r = i >> 7, off = (i & 127) * 8;
        int src = sp[r];
        uint4 v = make_uint4(0, 0, 0, 0);
        if (src >= 0)
            v = *(const uint4*)(xi + ((size_t)(b * 1024 + src)) * 1024 + off);
        *(uint4*)&rows[r][off] = v;
    }
    int e0 = threadIdx.x * 4;
    float w[4][4];
#pragma unroll
    for (int ee = 0; ee < 4; ee++)
#pragma unroll
        for (int k = 0; k < 4; k++)
            w[ee][k] = ldf(cw, (size_t)(e0 + ee) * 4 + k, fin);
    __syncthreads();
#pragma unroll
    for (int t = 0; t < CTB; t++) {
        float a[4] = {0.f, 0.f, 0.f, 0.f};
#pragma unroll
        for (int k = 0; k < 4; k++) {
            uint2 v = *(const uint2*)&rows[t + k][e0];
            const u16* vs = (const u16*)&v;
#pragma unroll
            for (int ee = 0; ee < 4; ee++)
                a[ee] += w[ee][k] * bf2f(vs[ee]);
        }
        u16 o[4];
#pragma unroll
        for (int ee = 0; ee < 4; ee++) o[ee] = f2bf(a[ee] * sigmoidf_(a[ee]));
        *(uint2*)(xc + ((size_t)(b * 1024 + t0 + t)) * 1024 + e0) = *(const uint2*)o;
    }
}

// ---------------- chunked parallel scan -------------------------------------
// grid per direction: (ec 4) x (chunk 32) x (b 8) = 1024 blocks x 256 threads.
// PASS3 reads z gathered through P_d (z kept in natural order).
template <int PASS>
__global__ __launch_bounds__(256) void scan_chunk(const float* __restrict__ dtbc,
                                                  u16* __restrict__ xcyz,
                                                  const u16* __restrict__ zb,
                                                  const void* __restrict__ A_log,
                                                  const void* __restrict__ W_dt,
                                                  const void* __restrict__ b_dt,
                                                  const int* __restrict__ flags,
                                                  float* __restrict__ hend,
                                                  float* __restrict__ dtsum,
                                                  int dbase,
                                                  const int* __restrict__ perm3) {
    int fin = flags[0];
    int bid = blockIdx.x;
    int ec = bid & 3, c = (bid >> 2) & 31, b = bid >> 7;
    int e = ec * 256 + threadIdx.x;
    __shared__ float sdt[CLEN][32];
    __shared__ int s_perm[CLEN];
    {
        const float* src = dtbc + ((size_t)b * 1024 + c * CLEN) * 64;
        int t = threadIdx.x >> 3, f = threadIdx.x & 7;   // 256 thr = 32 rows x 8 f4
        *(float4*)&sdt[t][f * 4] = *(const float4*)(src + (size_t)t * 64 + f * 4);
        if (PASS == 3 && threadIdx.x < CLEN)
            s_perm[threadIdx.x] = dirmap(dbase, c * CLEN + (int)threadIdx.x, perm3);
    }
    float Ae[16], wdt[16];
#pragma unroll
    for (int s = 0; s < 16; s++) Ae[s] = -__expf(ldf(A_log, (size_t)e * 16 + s, fin));
#pragma unroll
    for (int s = 0; s < 16; s++) wdt[s] = ldf(W_dt, (size_t)s * 1024 + e, fin);
    float bd = ldf(b_dt, e, fin);
    float h[16];
    if (PASS == 1) {
#pragma unroll
        for (int s = 0; s < 16; s++) h[s] = 0.f;
    } else {
#pragma unroll
        for (int s = 0; s < 16; s++)
            h[s] = hend[(((size_t)(b * NCHUNK + c)) * 16 + s) * 1024 + e];
    }
    __syncthreads();
    float ds = 0.f;
    size_t ix = ((size_t)b * 1024 + c * CLEN) * 1024 + e;
    size_t zbase = (size_t)b * 1024 * 1024 + e;
    float xv = bf2f(xcyz[ix]);                       // prefetch t=0
    float zv = (PASS == 3) ? bf2f(zb[zbase + (size_t)s_perm[0] * 1024]) : 0.f;
    for (int t = 0; t < CLEN; t++) {
        float xn = 0.f, zn = 0.f;
        if (t + 1 < CLEN) {                          // prefetch t+1
            xn = bf2f(xcyz[ix + 1024]);
            if (PASS == 3) zn = bf2f(zb[zbase + (size_t)s_perm[t + 1] * 1024]);
        }
        float4 d0 = *(const float4*)&sdt[t][0];
        float4 d1 = *(const float4*)&sdt[t][4];
        float4 d2 = *(const float4*)&sdt[t][8];
        float4 d3 = *(const float4*)&sdt[t][12];
        float xp = bd;
        xp += d0.x * wdt[0] + d0.y * wdt[1] + d0.z * wdt[2] + d0.w * wdt[3];
        xp += d1.x * wdt[4] + d1.y * wdt[5] + d1.z * wdt[6] + d1.w * wdt[7];
        xp += d2.x * wdt[8] + d2.y * wdt[9] + d2.z * wdt[10] + d2.w * wdt[11];
        xp += d3.x * wdt[12] + d3.y * wdt[13] + d3.z * wdt[14] + d3.w * wdt[15];
        float ex = __expf(xp);
        float dtv = (xp > 15.f) ? xp : __logf(1.f + ex);   // fast softplus
        float4 b0 = *(const float4*)&sdt[t][16];
        float4 b1 = *(const float4*)&sdt[t][20];
        float4 b2 = *(const float4*)&sdt[t][24];
        float4 b3 = *(const float4*)&sdt[t][28];
        float bc[16] = {b0.x, b0.y, b0.z, b0.w, b1.x, b1.y, b1.z, b1.w,
                        b2.x, b2.y, b2.z, b2.w, b3.x, b3.y, b3.z, b3.w};
        float acc = 0.f;
#pragma unroll
        for (int s = 0; s < 16; s++) {
            h[s] = h[s] * __expf(Ae[s] * dtv) + bc[s] * xv;
            acc += h[s];
        }
        if (PASS == 1) ds += dtv;
        if (PASS == 3) {
            xcyz[ix] = f2bf(acc * (zv * sigmoidf_(zv)));
        }
        ix += 1024;
        xv = xn;
        zv = zn;
    }
    if (PASS == 1) {
#pragma unroll
        for (int s = 0; s < 16; s++)
            hend[(((size_t)(b * NCHUNK + c)) * 16 + s) * 1024 + e] = h[s];
        dtsum[((size_t)(b * NCHUNK + c)) * 1024 + e] = ds;
    }
}

// combine parallelized over (b, s, ec): 512 blocks, each thread owns one
// (b,e,s) chain; sequential over c with 1 load + 1 exp + 1 store per step.
__global__ __launch_bounds__(256) void scan_combine2(float* __restrict__ hend,
                                                     const float* __restrict__ dtsum,
                                                     const void* __restrict__ A_log,
                                                     const int* __restrict__ flags) {
    int fin = flags[0];
    int bid = blockIdx.x;            // b*64 + s*4 + ec
    int ec = bid & 3, s = (bid >> 2) & 15, b = bid >> 6;
    int e = ec * 256 + threadIdx.x;
    float Ae = -__expf(ldf(A_log, (size_t)e * 16 + s, fin));
    float H = 0.f;
    for (int c = 0; c < NCHUNK; c++) {
        float ds = dtsum[((size_t)(b * NCHUNK + c)) * 1024 + e];
        size_t idx = (((size_t)(b * NCHUNK + c)) * 16 + s) * 1024 + e;
        float loc = hend[idx];
        hend[idx] = H;
        H = loc + __expf(Ae * ds) * H;
    }
}

// ---------------- LayerNorm over fused fp32 accumulator ---------------------
__global__ __launch_bounds__(256) void ln_kernel(const float* __restrict__ facc,
                                                 const void* __restrict__ ln_g,
                                                 const void* __restrict__ ln_b,
                                                 const int* __restrict__ flags,
                                                 u16* __restrict__ fn) {
    int fin = flags[0];
    size_t base = (size_t)blockIdx.x * 1024;
    float v[4];
    float sum = 0.f, sq = 0.f;
#pragma unroll
    for (int k = 0; k < 4; k++) {
        int e = threadIdx.x + k * 256;
        float f = facc[base + e];
        v[k] = f;
        sum += f;
        sq += f * f;
    }
    __shared__ float r1[256], r2[256];
    r1[threadIdx.x] = sum;
    r2[threadIdx.x] = sq;
    __syncthreads();
    for (int s = 128; s > 0; s >>= 1) {
        if (threadIdx.x < s) {
            r1[threadIdx.x] += r1[threadIdx.x + s];
            r2[threadIdx.x] += r2[threadIdx.x + s];
        }
        __syncthreads();
    }
    float mu = r1[0] * (1.f / 1024.f);
    float var = r2[0] * (1.f / 1024.f) - mu * mu;
    float rs = rsqrtf(var + 1e-5f);
#pragma unroll
    for (int k = 0; k < 4; k++) {
        int e = threadIdx.x + k * 256;
        fn[base + e] = f2bf((v[k] - mu) * rs * ldf(ln_g, e, fin) + ldf(ln_b, e, fin));
    }
}

// ---------------- gate: partial col sums -> shared matvec -> finisher -------
__global__ __launch_bounds__(256) void gate_partial(const u16* __restrict__ vfb,
                                                    float* __restrict__ meanv) {
    int b = blockIdx.x >> 4, tc = blockIdx.x & 15;
    float s[4] = {0.f, 0.f, 0.f, 0.f};
    const u16* base = vfb + ((size_t)b * 1024 + tc * 64) * 1024;
    for (int t = 0; t < 64; t++) {
#pragma unroll
        for (int k = 0; k < 4; k++)
            s[k] += bf2f(base[(size_t)t * 1024 + threadIdx.x + k * 256]);
    }
#pragma unroll
    for (int k = 0; k < 4; k++)
        atomicAdd(&meanv[b * 1024 + threadIdx.x + k * 256], s[k]);
}

__global__ __launch_bounds__(256) void gate_mv(const float* __restrict__ meanv,
                                               const void* __restrict__ Wg1,
                                               const int* __restrict__ flags,
                                               float* __restrict__ gpart) {
    int fin = flags[0];
    int kc = blockIdx.x, j = threadIdx.x;
    __shared__ float mv[8][32];
    if (threadIdx.x < 8 * 32) {
        int b = threadIdx.x >> 5, kk = threadIdx.x & 31;
        mv[b][kk] = meanv[b * 1024 + kc * 32 + kk] * (1.f / 1024.f);
    }
    __syncthreads();
    float acc[8];
#pragma unroll
    for (int b = 0; b < 8; b++) acc[b] = 0.f;
    for (int kk = 0; kk < 32; kk++) {
        float w = ldf(Wg1, (size_t)(kc * 32 + kk) * 256 + j, fin);
#pragma unroll
        for (int b = 0; b < 8; b++) acc[b] += mv[b][kk] * w;
    }
#pragma unroll
    for (int b = 0; b < 8; b++) atomicAdd(&gpart[b * 256 + j], acc[b]);
}

__global__ __launch_bounds__(256) void gate_fin2(const float* __restrict__ gpart,
                                                 const void* __restrict__ Wg2,
                                                 const int* __restrict__ flags,
                                                 float* __restrict__ g) {
    int fin = flags[0];
    int b = blockIdx.x, j = threadIdx.x;
    __shared__ float red[256];
    float a = gpart[b * 256 + j];
    float si = a * sigmoidf_(a);
    red[j] = si * ldf(Wg2, j, fin);
    __syncthreads();
    for (int st = 128; st > 0; st >>= 1) {
        if (j < st) red[j] += red[j + st];
        __syncthreads();
    }
    if (j == 0) g[b] = sigmoidf_(red[0]);
}

// ---------------- launch ----------------------------------------------------
extern "C" void kernel_launch(void* const* d_in, const int* in_sizes, int n_in,
                              void* d_out, int out_size, void* d_ws, size_t ws_size,
                              hipStream_t stream) {
    const void* vf_raw  = d_in[0];
    const void* W_input = d_in[1];
    const void* W_in    = d_in[2];
    const void* conv_w  = d_in[3];
    const void* W_xproj = d_in[4];
    const void* W_dt    = d_in[5];
    const void* b_dt    = d_in[6];
    const void* A_log   = d_in[7];
    const void* W_outm  = d_in[8];
    const void* dir_w   = d_in[9];
    const void* ln_g    = d_in[10];
    const void* ln_b    = d_in[11];
    const void* W_outpj = d_in[12];
    const void* Wg1     = d_in[13];
    const void* Wg2     = d_in[14];

    char* ws = (char*)d_ws;
    size_t off = 0;
    auto alloc = [&](size_t bytes) -> void* {
        void* p = ws + off;
        off = (off + bytes + 255) & ~(size_t)255;
        return p;
    };
    int*   flags = (int*)alloc(256);
    int*   perm3 = (int*)alloc(NN * 4);
    int*   inv3  = (int*)alloc(NN * 4);
    float* meanv = (float*)alloc(8 * 1024 * 4);
    float* gpart = (float*)alloc(8 * 256 * 4);
    float* gbuf  = (float*)alloc(64);
    float* dtsum = (float*)alloc((size_t)8 * NCHUNK * 1024 * 4);  // 1 MB
    u16*   WtI   = (u16*)alloc((size_t)1024 * 1024 * 2);
    u16*   WtIn  = (u16*)alloc((size_t)2048 * 1024 * 2);
    u16*   WtXp  = (u16*)alloc((size_t)64 * 1024 * 2);
    u16*   WtOm  = (u16*)alloc((size_t)1024 * 1024 * 2);
    u16*   WtOp  = (u16*)alloc((size_t)1024 * 1024 * 2);
    u16*   vfb   = (u16*)alloc((size_t)M1 * 1024 * 2);   // 16.78 MB; hend aliases
    u16*   xbuf  = (u16*)alloc((size_t)M1 * 1024 * 2);
    float* facc  = (float*)alloc((size_t)M1 * 1024 * 4);
    u16*   xi    = (u16*)alloc((size_t)M1 * 1024 * 2);   // later: fn
    u16*   zb    = (u16*)alloc((size_t)M1 * 1024 * 2);
    u16*   xc    = (u16*)alloc((size_t)M1 * 1024 * 2);   // per-d; yz in-place
    float* dtbc  = (float*)alloc((size_t)M1 * 64 * 4);
    // hend = 8*32*16*1024 f32 = 16.78 MB == vfb exactly (vfb dead after stage-1)
    float* hend  = (float*)vfb;

    detect_dtype<<<1, 64, 0, stream>>>((const u16*)vf_raw, flags);
    convert_bf<<<(M1 * 1024) / 256, 256, 0, stream>>>(vf_raw, vfb, flags, M1 * 1024);
    diag_perm_init<<<4, 256, 0, stream>>>(perm3, inv3);
    transpose_pad<<<dim3(32, 32), 256, 0, stream>>>(W_input, WtI, 1024, 1024, flags);
    transpose_pad<<<dim3(32, 64), 256, 0, stream>>>(W_in, WtIn, 1024, 2048, flags);
    transpose_pad<<<dim3(32, 2), 256, 0, stream>>>(W_xproj, WtXp, 1024, 32, flags);
    transpose_pad<<<dim3(32, 32), 256, 0, stream>>>(W_outm, WtOm, 1024, 1024, flags);
    transpose_pad<<<dim3(32, 32), 256, 0, stream>>>(W_outpj, WtOp, 1024, 1024, flags);
    zero_f32<<<(M1 * 1024) / 256, 256, 0, stream>>>(facc, M1 * 1024);
    zero_f32<<<32, 256, 0, stream>>>(meanv, 8 * 1024);
    zero_f32<<<8, 256, 0, stream>>>(gpart, 8 * 256);

    // gate (uses vfb before hend aliases it — stream-ordered)
    gate_partial<<<128, 256, 0, stream>>>(vfb, meanv);
    gate_mv<<<32, 256, 0, stream>>>(meanv, Wg1, flags, gpart);
    gate_fin2<<<8, 256, 0, stream>>>(gpart, Wg2, flags, gbuf);

    // stage 1: x = vf @ W_input
    gemm128<0><<<dim3(64, 8), 256, 0, stream>>>(
        vfb, WtI, xbuf, nullptr, M1, 1024, 1024, perm3, flags, 0, nullptr, nullptr);
    // stage 2 (once — gather commutes with the GEMM): xz = x @ W_in -> xi, z
    gemm128<1><<<dim3(64, 16), 256, 0, stream>>>(
        xbuf, WtIn, xi, zb, M1, 2048, 1024, perm3, flags, 0, nullptr, nullptr);

    for (int d = 0; d < 4; d++) {
        conv_tile<<<1024, 256, 0, stream>>>(xi, conv_w, xc, flags, d, perm3);
        zero_f32<<<(M1 * 64) / 256, 256, 0, stream>>>(dtbc, M1 * 64);
        gemm_dtbc_ks<<<dim3(128, 8), 256, 0, stream>>>(xc, WtXp, dtbc, M1, 64, 1024);
        scan_chunk<1><<<1024, 256, 0, stream>>>(dtbc, xc, zb, A_log, W_dt, b_dt,
                                                flags, hend, dtsum, d, perm3);
        scan_combine2<<<512, 256, 0, stream>>>(hend, dtsum, A_log, flags);
        scan_chunk<3><<<1024, 256, 0, stream>>>(dtbc, xc, zb, A_log, W_dt, b_dt,
                                                flags, hend, dtsum, d, perm3);
        gemm128<3><<<dim3(64, 8), 256, 0, stream>>>(
            xc, WtOm, facc, nullptr, M1, 1024, 1024, perm3, flags, d, dir_w, nullptr);
    }

    u16* fn = xi;  // xi dead after d=3 conv
    ln_kernel<<<M1, 256, 0, stream>>>(facc, ln_g, ln_b, flags, fn);
    gemm128<4><<<dim3(64, 8), 256, 0, stream>>>(
        fn, WtOp, d_out, nullptr, M1, 1024, 1024, perm3, flags, 0, vf_raw, gbuf);
}